// Round 2
// baseline (591.004 us; speedup 1.0000x reference)
//
#include <hip/hip_runtime.h>

#define TT 512
#define BIGS 1.4426950408889634e10f   // BIG(1e10) * log2(e), scaled domain
#define LOG2E 1.4426950408889634f
#define M2L  (-2.0f * 1.4426950408889634f)
#define LN2F 0.69314718055994531f
#define P_SS 16                       // ticks per superstep (barrier period)
#define G_LAG 80                      // band lag in ticks (>= P_SS + 63 + 1)
#define N_SS 51                       // band3 last tick 574 at s=50

typedef _Float16 h2 __attribute__((ext_vector_type(2)));

__device__ __forceinline__ unsigned pk(float a, float b) {
    h2 v; v.x = (_Float16)a; v.y = (_Float16)b;
    return __builtin_bit_cast(unsigned, v);
}

#if __has_builtin(__builtin_amdgcn_fdot2)
#define FDOT2(a, b, c) __builtin_amdgcn_fdot2(__builtin_bit_cast(h2, (a)), \
                                              __builtin_bit_cast(h2, (b)), (c), false)
#else
__device__ __forceinline__ float fdot2_sw(unsigned a, unsigned b, float c) {
    h2 ha = __builtin_bit_cast(h2, a), hb = __builtin_bit_cast(h2, b);
    return c + (float)ha.x * (float)hb.x + (float)ha.y * (float)hb.y;
}
#define FDOT2(a, b, c) fdot2_sw((a), (b), (c))
#endif

// permuted Z index, pure bitops (valid for any int j; wraps out-of-range j
// onto some valid row -- garbage rows only feed inactive ticks)
#define ZROW(jv) (((((jv) & 1)) << 8) | ((((jv) >> 1)) & 255))

// ---------------------------------------------------------------------------
// Round 12: revert the round-11 production hoist (ticks are latency-bound,
// not issue-bound: the in-tick FDOT2s were free in the stall shadow; the
// hoist re-paid them as serial issue time, 203->257us).
// New lever: TLP. 4 samples per block (16 blocks x 1024 threads = 16 waves
// = 4 waves/SIMD). Tick/schedule/seam structure identical to the verified
// round-10 kernel; only the mapping changes:
//   * smp = tt>>8 selects the sample; wave-in-sample wv = (tt>>6)&3
//   * ZA/Zs2p staged once, SHARED across the 4 samples (same Z)
//   * seam rings per sample: seamK[4][4][64]
// Each SIMD interleaves 4 independent DP waves -> lgkmcnt/dependency stalls
// of one wave are filled by the others (active-CU VALUBusy ~45% -> ~90%).
// ---------------------------------------------------------------------------
__global__ __launch_bounds__(1024, 1) void k_fused(const float* __restrict__ X,
                                                   const float* __restrict__ Z,
                                                   const float* __restrict__ w,
                                                   float* __restrict__ out) {
    const int tt  = threadIdx.x;
    const int t   = tt & 63;          // lane
    const int wv  = (tt >> 6) & 3;    // wave-in-sample = row band 0..3
    const int smp = tt >> 8;          // sample slot 0..3
    const int n   = (blockIdx.x << 2) + smp;   // sample

    __shared__ uint4 ZA[2][512];      // Z rows fp16-packed, permuted idx (shared)
    __shared__ float Zs2p[512];       // LOG2E*|z|^2 at permuted idx (shared)
    __shared__ float seamK[4][4][64]; // per-sample seam rings (K)
    __shared__ float seamS[4][4][64]; // per-sample seam rings (sm)

    // ---- stage Z into LDS: threads 0..511 handle one row each ----
    if (tt < 512) {
        const int r = tt;
        const float4* zp = (const float4*)(Z + (size_t)r * 16);
        const float4 a0 = zp[0], a1 = zp[1], a2 = zp[2], a3 = zp[3];
        float sv = 0.0f;
        sv = fmaf(a0.x, a0.x, sv); sv = fmaf(a0.y, a0.y, sv);
        sv = fmaf(a0.z, a0.z, sv); sv = fmaf(a0.w, a0.w, sv);
        sv = fmaf(a1.x, a1.x, sv); sv = fmaf(a1.y, a1.y, sv);
        sv = fmaf(a1.z, a1.z, sv); sv = fmaf(a1.w, a1.w, sv);
        sv = fmaf(a2.x, a2.x, sv); sv = fmaf(a2.y, a2.y, sv);
        sv = fmaf(a2.z, a2.z, sv); sv = fmaf(a2.w, a2.w, sv);
        sv = fmaf(a3.x, a3.x, sv); sv = fmaf(a3.y, a3.y, sv);
        sv = fmaf(a3.z, a3.z, sv); sv = fmaf(a3.w, a3.w, sv);
        const int idx = ((r & 1) << 8) | (r >> 1);
        ZA[0][idx] = make_uint4(pk(a0.x, a0.y), pk(a0.z, a0.w),
                                pk(a1.x, a1.y), pk(a1.z, a1.w));
        ZA[1][idx] = make_uint4(pk(a2.x, a2.y), pk(a2.z, a2.w),
                                pk(a3.x, a3.y), pk(a3.z, a3.w));
        Zs2p[idx] = LOG2E * sv;
    }
    // seam rings -> (BIGS, 1): matrix border; band-0 rings never written.
    // 4*4*64 = 1024 entries == blockDim
    (&seamK[0][0][0])[tt] = BIGS;
    (&seamS[0][0][0])[tt] = 1.0f;

    // ---- X rows for this lane (rows i0, i0+1) -> registers ----
    const int i0 = 128 * wv + 2 * t;
    unsigned Xu[2][8];
    float    xs2[2];
    const float* xp = X + ((size_t)n * TT + i0) * 16;
#pragma unroll
    for (int q = 0; q < 2; ++q) {
        const float4* xr = (const float4*)(xp + q * 16);
        const float4 a0 = xr[0], a1 = xr[1], a2 = xr[2], a3 = xr[3];
        float sv = 0.0f;
        sv = fmaf(a0.x, a0.x, sv); sv = fmaf(a0.y, a0.y, sv);
        sv = fmaf(a0.z, a0.z, sv); sv = fmaf(a0.w, a0.w, sv);
        sv = fmaf(a1.x, a1.x, sv); sv = fmaf(a1.y, a1.y, sv);
        sv = fmaf(a1.z, a1.z, sv); sv = fmaf(a1.w, a1.w, sv);
        sv = fmaf(a2.x, a2.x, sv); sv = fmaf(a2.y, a2.y, sv);
        sv = fmaf(a2.z, a2.z, sv); sv = fmaf(a2.w, a2.w, sv);
        sv = fmaf(a3.x, a3.x, sv); sv = fmaf(a3.y, a3.y, sv);
        sv = fmaf(a3.z, a3.z, sv); sv = fmaf(a3.w, a3.w, sv);
        xs2[q] = LOG2E * sv;
        Xu[q][0] = pk(a0.x, a0.y); Xu[q][1] = pk(a0.z, a0.w);
        Xu[q][2] = pk(a1.x, a1.y); Xu[q][3] = pk(a1.z, a1.w);
        Xu[q][4] = pk(a2.x, a2.y); Xu[q][5] = pk(a2.z, a2.w);
        Xu[q][6] = pk(a3.x, a3.y); Xu[q][7] = pk(a3.z, a3.w);
    }
    const float wgt = w[n];
    const float* rK = &seamK[smp][wv][0];
    const float* rS = &seamS[smp][wv][0];
    __syncthreads();

    float RpK[2], RpS[2], poK, poS, smK, smS, bnK, bnS;
    uint4 Zb[2][2];
    float zsb[2];
    RpK[0] = RpK[1] = BIGS; RpS[0] = RpS[1] = 1.0f;
    poK = BIGS; poS = 1.0f; smK = BIGS; smS = 1.0f;
    bnK = BIGS; bnS = 1.0f;
    zsb[0] = zsb[1] = 0.0f;
    Zb[0][0] = Zb[0][1] = Zb[1][0] = Zb[1][1] = make_uint4(0, 0, 0, 0);

#define TICK(par, tl)                                                          \
    {                                                                          \
        const float unK = (t == 0) ? smK : bnK;                                \
        const float unS = (t == 0) ? smS : bnS;                                \
        smK = rK[((tl) + 1) & 63];           /* seam for next tick */          \
        smS = rS[((tl) + 1) & 63];                                             \
        const uint4 z0 = Zb[par][0], z1 = Zb[par][1];                          \
        const float zz = zsb[par];                                             \
        {   /* refill this slot with the row for tick tl+2 */                  \
            const int xn = ZROW((tl) + 2 - t);                                 \
            Zb[par][0] = ZA[0][xn];                                            \
            Zb[par][1] = ZA[1][xn];                                            \
            zsb[par] = Zs2p[xn];                                               \
        }                                                                      \
        float a0 = 0.0f, a1 = 0.0f;                                            \
        a0 = FDOT2(z0.x, Xu[0][0], a0); a0 = FDOT2(z0.y, Xu[0][1], a0);        \
        a0 = FDOT2(z0.z, Xu[0][2], a0); a0 = FDOT2(z0.w, Xu[0][3], a0);        \
        a0 = FDOT2(z1.x, Xu[0][4], a0); a0 = FDOT2(z1.y, Xu[0][5], a0);        \
        a0 = FDOT2(z1.z, Xu[0][6], a0); a0 = FDOT2(z1.w, Xu[0][7], a0);        \
        a1 = FDOT2(z0.x, Xu[1][0], a1); a1 = FDOT2(z0.y, Xu[1][1], a1);        \
        a1 = FDOT2(z0.z, Xu[1][2], a1); a1 = FDOT2(z0.w, Xu[1][3], a1);        \
        a1 = FDOT2(z1.x, Xu[1][4], a1); a1 = FDOT2(z1.y, Xu[1][5], a1);        \
        a1 = FDOT2(z1.z, Xu[1][6], a1); a1 = FDOT2(z1.w, Xu[1][7], a1);        \
        const float dd0 = fmaf(M2L, a0, xs2[0] + zz);                          \
        const float dd1 = fmaf(M2L, a1, xs2[1] + zz);                          \
        /* (K,sm) softmin, unconditional (all operands finite) */              \
        const float l0K = RpK[0], l0S = RpS[0];                                \
        const float m0 = fminf(fminf(unK, l0K), poK);                          \
        const float s0 = exp2f(m0 - unK) * unS                                 \
                       + exp2f(m0 - l0K) * l0S                                 \
                       + exp2f(m0 - poK) * poS;                                \
        const float K0 = dd0 + m0;                                             \
        const float l1K = RpK[1], l1S = RpS[1];                                \
        const float m1 = fminf(fminf(K0, l1K), l0K);                           \
        const float s1 = exp2f(m1 - K0) * s0                                   \
                       + exp2f(m1 - l1K) * l1S                                 \
                       + exp2f(m1 - l0K) * l0S;                                \
        const float K1 = dd1 + m1;                                             \
        const int j = (tl) - t;                                                \
        const bool ok = (j >= 0) && (j < 512);                                 \
        RpK[0] = ok ? K0 : RpK[0];  RpS[0] = ok ? s0 : RpS[0];                 \
        RpK[1] = ok ? K1 : RpK[1];  RpS[1] = ok ? s1 : RpS[1];                 \
        if (ok && wv < 3 && t == 63) {                                         \
            seamK[smp][wv + 1][j & 63] = RpK[1];                               \
            seamS[smp][wv + 1][j & 63] = RpS[1];                               \
        }                                                                      \
        poK = unK; poS = unS;                                                  \
        bnK = __shfl_up(RpK[1], 1);          /* boundary for tick tl+1 */      \
        bnS = __shfl_up(RpS[1], 1);                                            \
    }

#define RENORM                                                                 \
    {                                                                          \
        _Pragma("unroll")                                                      \
        for (int q = 0; q < 2; ++q) {                                          \
            const int e = (int)(__float_as_uint(RpS[q]) >> 23) - 127;          \
            RpS[q] = __uint_as_float(__float_as_uint(RpS[q])                   \
                                     - ((unsigned)e << 23));                   \
            RpK[q] -= (float)e;                                                \
        }                                                                      \
    }

#pragma unroll 1
    for (int s = 0; s < N_SS; ++s) {
        const int tb = P_SS * s - G_LAG * wv;
        if (tb >= 0 && tb <= 574) {
            if (tb == 0) {
                // activation: state + boundary + Z buffers for ticks 0,1
                RpK[0] = RpK[1] = BIGS; RpS[0] = RpS[1] = 1.0f;
                poK = (wv == 0 && t == 0) ? 0.0f : BIGS; poS = 1.0f;  // corner
                bnK = BIGS; bnS = 1.0f;
                smK = rK[0]; smS = rS[0];
                const int x0 = ZROW(0 - t);
                const int x1 = ZROW(1 - t);
                Zb[0][0] = ZA[0][x0]; Zb[0][1] = ZA[1][x0]; zsb[0] = Zs2p[x0];
                Zb[1][0] = ZA[0][x1]; Zb[1][1] = ZA[1][x1]; zsb[1] = Zs2p[x1];
            }
            TICK(0, tb + 0)  TICK(1, tb + 1)  TICK(0, tb + 2)  TICK(1, tb + 3)
            TICK(0, tb + 4)  TICK(1, tb + 5)  TICK(0, tb + 6)  TICK(1, tb + 7)
            RENORM
            TICK(0, tb + 8)  TICK(1, tb + 9)  TICK(0, tb + 10) TICK(1, tb + 11)
            TICK(0, tb + 12) TICK(1, tb + 13) TICK(0, tb + 14) TICK(1, tb + 15)
            RENORM
        }
        __syncthreads();
    }
#undef TICK
#undef RENORM

    // band 3, lane 63, row 511 at tick 574 -> R(511,511) = K - log2(sm)
    if (wv == 3 && t == 63) {
        atomicAdd(out, wgt * (RpK[1] - log2f(RpS[1])) * LN2F);
    }
}

__global__ void k_zero(float* out) {
    if (threadIdx.x == 0) out[0] = 0.0f;
}

extern "C" void kernel_launch(void* const* d_in, const int* in_sizes, int n_in,
                              void* d_out, int out_size, void* d_ws, size_t ws_size,
                              hipStream_t stream) {
    const float* X = (const float*)d_in[0];   // (64, 512, 16) f32
    const float* w = (const float*)d_in[1];   // (64,) f32
    const float* Z = (const float*)d_in[2];   // (512, 16) f32
    float* out = (float*)d_out;               // scalar f32

    hipLaunchKernelGGL(k_zero, dim3(1), dim3(64), 0, stream, out);
    hipLaunchKernelGGL(k_fused, dim3(16), dim3(1024), 0, stream, X, Z, w, out);
}

// Round 3
// 316.577 us; speedup vs baseline: 1.8669x; 1.8669x over previous
//
#include <hip/hip_runtime.h>

#define TT 512
#define BIGS 1.4426950408889634e10f   // BIG(1e10) * log2(e), scaled domain
#define LOG2E 1.4426950408889634f
#define M2L  (-2.0f * 1.4426950408889634f)
#define LN2F 0.69314718055994531f
#define P_SS 16                       // ticks per superstep (barrier period)
#define G_LAG 96                      // band lag; >= P_SS+63+prefetch(2)+1 = 82, rounded to 6 supersteps
#define N_SS 78                       // band7: ticks 672..1247; 78*16 = 1248
#define NB 8                          // bands (64 rows each, 1 row per lane)

typedef _Float16 h2 __attribute__((ext_vector_type(2)));

__device__ __forceinline__ unsigned pk(float a, float b) {
    h2 v; v.x = (_Float16)a; v.y = (_Float16)b;
    return __builtin_bit_cast(unsigned, v);
}

#if __has_builtin(__builtin_amdgcn_fdot2)
#define FDOT2(a, b, c) __builtin_amdgcn_fdot2(__builtin_bit_cast(h2, (a)), \
                                              __builtin_bit_cast(h2, (b)), (c), false)
#else
__device__ __forceinline__ float fdot2_sw(unsigned a, unsigned b, float c) {
    h2 ha = __builtin_bit_cast(h2, a), hb = __builtin_bit_cast(h2, b);
    return c + (float)ha.x * (float)hb.x + (float)ha.y * (float)hb.y;
}
#define FDOT2(a, b, c) fdot2_sw((a), (b), (c))
#endif

// permuted Z index, pure bitops (valid for any int j; wraps out-of-range j
// onto some valid row -- garbage rows only feed masked ticks)
#define ZROW(jv) (((((jv) & 1)) << 8) | ((((jv) >> 1)) & 255))

// lane-shift-up-by-1 via DPP wave_shr:1 (VALU, ~4cy) instead of ds_permute
// (~120cy LDS latency on the loop-carried path). Lane 0 takes `old` --
// which we feed the seam value, folding the (t==0) select in for free.
__device__ __forceinline__ float dppshr1(float x, float old) {
#if __has_builtin(__builtin_amdgcn_update_dpp)
    return __builtin_bit_cast(float,
        __builtin_amdgcn_update_dpp(__builtin_bit_cast(int, old),
                                    __builtin_bit_cast(int, x),
                                    0x138 /*wave_shr:1*/, 0xF, 0xF, false));
#else
    const float v = __shfl_up(x, 1);
    return ((threadIdx.x & 63) == 0) ? old : v;
#endif
}

// ---------------------------------------------------------------------------
// Round 13: within-sample TLP + loop-chain surgery.
//  * 8 bands x 64 rows, 1 row/lane, 512 thr/block, 64 blocks -> 2 waves/SIMD
//    on ALL 64 CUs (r12 proved stall-filling works but wasted 3/4 of the
//    CUs on sample-packing; only-64-samples => TLP must be intra-sample).
//  * Band index remapped (SIMD k hosts adjacent bands 2k,2k+1, lag 6 ss)
//    so paired waves overlap in 30/36 active supersteps.
//  * Boundary pass R[i-1,j]: DPP wave_shr:1 (VALU) replaces __shfl_up
//    (ds_permute, ~120cy latency measured m117) on the loop-carried chain;
//    seam value rides the DPP `old` operand (kills the t==0 cndmask too).
//  * Seam ring as float2 (1x ds_read_b64 per tick), prefetched 2 ticks
//    ahead; G_LAG 80->96 for the deeper prefetch (proof re-done).
// Per-cell DP recurrence, renorm, activation identical to verified rounds.
// ---------------------------------------------------------------------------
__global__ __launch_bounds__(512, 2) void k_fused(const float* __restrict__ X,
                                                  const float* __restrict__ Z,
                                                  const float* __restrict__ w,
                                                  float* __restrict__ out) {
    const int tt = threadIdx.x;
    const int t  = tt & 63;                      // lane
    const int wv = tt >> 6;                      // hw wave 0..7 (SIMD = wv&3)
    const int bd = ((wv & 3) << 1) | (wv >> 2);  // band: SIMD k <- bands 2k,2k+1
    const int n  = blockIdx.x;                   // sample

    __shared__ uint4  ZA[2][512];     // Z rows fp16-packed, permuted idx
    __shared__ float  Zs2p[512];      // LOG2E*|z|^2 at permuted idx
    __shared__ float2 seam[NB][64];   // seam rings (K, sm); band0 = border

    // ---- stage Z into LDS: thread tt handles row tt ----
    {
        const int r = tt;
        const float4* zp = (const float4*)(Z + (size_t)r * 16);
        const float4 a0 = zp[0], a1 = zp[1], a2 = zp[2], a3 = zp[3];
        float sv = 0.0f;
        sv = fmaf(a0.x, a0.x, sv); sv = fmaf(a0.y, a0.y, sv);
        sv = fmaf(a0.z, a0.z, sv); sv = fmaf(a0.w, a0.w, sv);
        sv = fmaf(a1.x, a1.x, sv); sv = fmaf(a1.y, a1.y, sv);
        sv = fmaf(a1.z, a1.z, sv); sv = fmaf(a1.w, a1.w, sv);
        sv = fmaf(a2.x, a2.x, sv); sv = fmaf(a2.y, a2.y, sv);
        sv = fmaf(a2.z, a2.z, sv); sv = fmaf(a2.w, a2.w, sv);
        sv = fmaf(a3.x, a3.x, sv); sv = fmaf(a3.y, a3.y, sv);
        sv = fmaf(a3.z, a3.z, sv); sv = fmaf(a3.w, a3.w, sv);
        const int idx = ((r & 1) << 8) | (r >> 1);
        ZA[0][idx] = make_uint4(pk(a0.x, a0.y), pk(a0.z, a0.w),
                                pk(a1.x, a1.y), pk(a1.z, a1.w));
        ZA[1][idx] = make_uint4(pk(a2.x, a2.y), pk(a2.z, a2.w),
                                pk(a3.x, a3.y), pk(a3.z, a3.w));
        Zs2p[idx] = LOG2E * sv;
    }
    // seam rings -> (BIGS, 1): matrix border; band-0 ring never written.
    ((float2*)&seam[0][0])[tt] = make_float2(BIGS, 1.0f);

    // ---- X row for this lane (row i0) -> registers ----
    const int i0 = (bd << 6) + t;
    unsigned Xu[8];
    float    xs2;
    {
        const float4* xr = (const float4*)(X + ((size_t)n * TT + i0) * 16);
        const float4 a0 = xr[0], a1 = xr[1], a2 = xr[2], a3 = xr[3];
        float sv = 0.0f;
        sv = fmaf(a0.x, a0.x, sv); sv = fmaf(a0.y, a0.y, sv);
        sv = fmaf(a0.z, a0.z, sv); sv = fmaf(a0.w, a0.w, sv);
        sv = fmaf(a1.x, a1.x, sv); sv = fmaf(a1.y, a1.y, sv);
        sv = fmaf(a1.z, a1.z, sv); sv = fmaf(a1.w, a1.w, sv);
        sv = fmaf(a2.x, a2.x, sv); sv = fmaf(a2.y, a2.y, sv);
        sv = fmaf(a2.z, a2.z, sv); sv = fmaf(a2.w, a2.w, sv);
        sv = fmaf(a3.x, a3.x, sv); sv = fmaf(a3.y, a3.y, sv);
        sv = fmaf(a3.z, a3.z, sv); sv = fmaf(a3.w, a3.w, sv);
        xs2 = LOG2E * sv;
        Xu[0] = pk(a0.x, a0.y); Xu[1] = pk(a0.z, a0.w);
        Xu[2] = pk(a1.x, a1.y); Xu[3] = pk(a1.z, a1.w);
        Xu[4] = pk(a2.x, a2.y); Xu[5] = pk(a2.z, a2.w);
        Xu[6] = pk(a3.x, a3.y); Xu[7] = pk(a3.z, a3.w);
    }
    const float wgt = w[n];
    const float2* rKS = &seam[bd][0];
    __syncthreads();

    float RpK = BIGS, RpS = 1.0f;    // R[i, j-1] (own state)
    float poK = BIGS, poS = 1.0f;    // R[i-1, j-1]
    float bnK = BIGS, bnS = 1.0f;    // R[i-1, j]  (DPP from lane-1 / seam)
    float2 smv[2];                   // seam prefetch slots (parity)
    smv[0] = smv[1] = make_float2(BIGS, 1.0f);
    uint4 Zb[2][2];                  // Z-row prefetch slots (parity)
    float zsb[2];
    zsb[0] = zsb[1] = 0.0f;
    Zb[0][0] = Zb[0][1] = Zb[1][0] = Zb[1][1] = make_uint4(0, 0, 0, 0);

#define TICK(par, tl)                                                          \
    {                                                                          \
        const float unK = bnK, unS = bnS;                                      \
        const float2 sprev = smv[(par) ^ 1];   /* ring[(tl+1)&63] */           \
        smv[par] = rKS[((tl) + 2) & 63];       /* for end of tick tl+1 */      \
        const uint4 z0 = Zb[par][0], z1 = Zb[par][1];                          \
        const float zz = zsb[par];                                             \
        {   /* refill this slot with the row for tick tl+2 */                  \
            const int xn = ZROW((tl) + 2 - t);                                 \
            Zb[par][0] = ZA[0][xn];                                            \
            Zb[par][1] = ZA[1][xn];                                            \
            zsb[par] = Zs2p[xn];                                               \
        }                                                                      \
        float a = 0.0f;                                                        \
        a = FDOT2(z0.x, Xu[0], a); a = FDOT2(z0.y, Xu[1], a);                  \
        a = FDOT2(z0.z, Xu[2], a); a = FDOT2(z0.w, Xu[3], a);                  \
        a = FDOT2(z1.x, Xu[4], a); a = FDOT2(z1.y, Xu[5], a);                  \
        a = FDOT2(z1.z, Xu[6], a); a = FDOT2(z1.w, Xu[7], a);                  \
        const float dd = fmaf(M2L, a, xs2 + zz);                               \
        /* (K,sm) softmin, unconditional (all operands finite) */              \
        const float lK = RpK, lS = RpS;                                        \
        const float m  = fminf(fminf(unK, lK), poK);                           \
        const float ss = exp2f(m - unK) * unS                                  \
                       + exp2f(m - lK) * lS                                    \
                       + exp2f(m - poK) * poS;                                 \
        const float K  = dd + m;                                               \
        const int j = (tl) - t;                                                \
        const bool ok = (j >= 0) && (j < 512);                                 \
        RpK = ok ? K : RpK;  RpS = ok ? ss : RpS;                              \
        if (ok && bd < 7 && t == 63) {                                         \
            seam[bd + 1][j & 63] = make_float2(RpK, RpS);                      \
        }                                                                      \
        poK = unK; poS = unS;                                                  \
        bnK = dppshr1(RpK, sprev.x);   /* boundary for tick tl+1 */            \
        bnS = dppshr1(RpS, sprev.y);                                           \
    }

#define RENORM                                                                 \
    {                                                                          \
        const int e = (int)(__float_as_uint(RpS) >> 23) - 127;                 \
        RpS = __uint_as_float(__float_as_uint(RpS) - ((unsigned)e << 23));     \
        RpK -= (float)e;                                                       \
    }

#pragma unroll 1
    for (int s = 0; s < N_SS; ++s) {
        const int tb = P_SS * s - G_LAG * bd;
        if (tb >= 0 && tb <= 574) {
            if (tb == 0) {
                // activation: state + boundary + seam/Z prefetch for ticks 0,1
                RpK = BIGS; RpS = 1.0f;
                poK = (bd == 0 && t == 0) ? 0.0f : BIGS; poS = 1.0f;  // corner
                const float2 r0 = rKS[0];
                bnK = r0.x; bnS = r0.y;   // un(tick0): lane0 real, rest masked
                smv[1] = rKS[1];          // sprev for tick 0 (-> un tick1)
                const int x0 = ZROW(0 - t);
                const int x1 = ZROW(1 - t);
                Zb[0][0] = ZA[0][x0]; Zb[0][1] = ZA[1][x0]; zsb[0] = Zs2p[x0];
                Zb[1][0] = ZA[0][x1]; Zb[1][1] = ZA[1][x1]; zsb[1] = Zs2p[x1];
            }
            TICK(0, tb + 0)  TICK(1, tb + 1)  TICK(0, tb + 2)  TICK(1, tb + 3)
            TICK(0, tb + 4)  TICK(1, tb + 5)  TICK(0, tb + 6)  TICK(1, tb + 7)
            RENORM
            TICK(0, tb + 8)  TICK(1, tb + 9)  TICK(0, tb + 10) TICK(1, tb + 11)
            TICK(0, tb + 12) TICK(1, tb + 13) TICK(0, tb + 14) TICK(1, tb + 15)
            RENORM
        }
        __syncthreads();
    }
#undef TICK
#undef RENORM

    // band 7, lane 63, row 511 at tick 574 -> R(511,511) = K - log2(sm)
    if (bd == 7 && t == 63) {
        atomicAdd(out, wgt * (RpK - log2f(RpS)) * LN2F);
    }
}

__global__ void k_zero(float* out) {
    if (threadIdx.x == 0) out[0] = 0.0f;
}

extern "C" void kernel_launch(void* const* d_in, const int* in_sizes, int n_in,
                              void* d_out, int out_size, void* d_ws, size_t ws_size,
                              hipStream_t stream) {
    const float* X = (const float*)d_in[0];   // (64, 512, 16) f32
    const float* w = (const float*)d_in[1];   // (64,) f32
    const float* Z = (const float*)d_in[2];   // (512, 16) f32
    float* out = (float*)d_out;               // scalar f32

    hipLaunchKernelGGL(k_zero, dim3(1), dim3(64), 0, stream, out);
    hipLaunchKernelGGL(k_fused, dim3(64), dim3(512), 0, stream, X, Z, w, out);
}

// Round 4
// 257.996 us; speedup vs baseline: 2.2907x; 1.2271x over previous
//
#include <hip/hip_runtime.h>

#define TT 512
#define BIGS 1.4426950408889634e10f   // BIG(1e10) * log2(e), scaled domain
#define LOG2E 1.4426950408889634f
#define M2L  (-2.0f * 1.4426950408889634f)
#define LN2F 0.69314718055994531f
#define P_SS 16                       // ticks per superstep (barrier period)
#define G_LAG 96                      // band lag; distance-3 seam prefetch needs
                                      // write->read margin > P_SS (see proof in comment)
#define N_SS 54                       // band3 last tick 574+288=862 -> s=53

typedef _Float16 h2 __attribute__((ext_vector_type(2)));

__device__ __forceinline__ unsigned pk(float a, float b) {
    h2 v; v.x = (_Float16)a; v.y = (_Float16)b;
    return __builtin_bit_cast(unsigned, v);
}

#if __has_builtin(__builtin_amdgcn_fdot2)
#define FDOT2(a, b, c) __builtin_amdgcn_fdot2(__builtin_bit_cast(h2, (a)), \
                                              __builtin_bit_cast(h2, (b)), (c), false)
#else
__device__ __forceinline__ float fdot2_sw(unsigned a, unsigned b, float c) {
    h2 ha = __builtin_bit_cast(h2, a), hb = __builtin_bit_cast(h2, b);
    return c + (float)ha.x * (float)hb.x + (float)ha.y * (float)hb.y;
}
#define FDOT2(a, b, c) fdot2_sw((a), (b), (c))
#endif

// permuted Z index, pure bitops (valid for any int j; wraps out-of-range j
// onto some valid row -- garbage rows only feed masked ticks)
#define ZROW(jv) (((((jv) & 1)) << 8) | ((((jv) >> 1)) & 255))

// lane-shift-up-by-1 via DPP wave_shr:1 (VALU, ~8cy) instead of ds_permute
// (~120cy latency) on the loop-carried path. Lane 0 takes `old`, which we
// feed the seam value -- folds the (t==0) select in for free. Verified r13.
__device__ __forceinline__ float dppshr1(float x, float old) {
#if __has_builtin(__builtin_amdgcn_update_dpp)
    return __builtin_bit_cast(float,
        __builtin_amdgcn_update_dpp(__builtin_bit_cast(int, old),
                                    __builtin_bit_cast(int, x),
                                    0x138 /*wave_shr:1*/, 0xF, 0xF, false));
#else
    const float v = __shfl_up(x, 1);
    return ((threadIdx.x & 63) == 0) ? old : v;
#endif
}

// ---------------------------------------------------------------------------
// Round 14: r10 structure (4 bands x 2 rows/lane, shortest pipeline, 64 CUs)
// with the loop-carried chain cut down:
//  * dd (distance) PIPELINED ONE TICK AHEAD: tick tl computes dd for tick
//    tl+1 from Z prefetched at distance 2. The softmin chain head has all
//    operands ready at tick start; the serial-FDOT2 dot chain (was ~130cy
//    in the middle of the carried chain) moves fully off-path. Dot split
//    into 2 independent 4-FDOT2 chains for latency safety.
//  * DPP wave_shr:1 boundary (r13-verified) replaces both __shfl_up
//    (~120cy ds_permute) at the chain tail; seam rides the DPP old operand.
//  * Seam ring as float2, prefetched at distance 3 ticks. G_LAG 80->96:
//    seam write (producer tick c+63+96bd) to read (consumer c-3+96(bd+1))
//    margin = 30 ticks > P_SS -> always a barrier between. Ring overwrite
//    margin 34. N_SS 51->54 (+6% ticks).
// Per-cell math, renorm, masks, activation semantics identical to verified
// rounds (chain: r10 ladder; DPP+float2 seam: r13, absmax 0).
// ---------------------------------------------------------------------------
__global__ __launch_bounds__(256, 1) void k_fused(const float* __restrict__ X,
                                                  const float* __restrict__ Z,
                                                  const float* __restrict__ w,
                                                  float* __restrict__ out) {
    const int tt = threadIdx.x;
    const int t  = tt & 63;          // lane
    const int wv = tt >> 6;          // wave = row band 0..3
    const int n  = blockIdx.x;       // sample

    __shared__ uint4  ZA[2][512];    // Z rows fp16-packed, permuted idx
    __shared__ float  Zs2p[512];     // LOG2E*|z|^2 at permuted idx
    __shared__ float2 seam[4][64];   // seam rings (K, sm); band0 = border

    // ---- stage Z into LDS: thread tt handles rows tt, tt+256 ----
#pragma unroll
    for (int h = 0; h < 2; ++h) {
        const int r = tt + h * 256;
        const float4* zp = (const float4*)(Z + (size_t)r * 16);
        const float4 a0 = zp[0], a1 = zp[1], a2 = zp[2], a3 = zp[3];
        float sv = 0.0f;
        sv = fmaf(a0.x, a0.x, sv); sv = fmaf(a0.y, a0.y, sv);
        sv = fmaf(a0.z, a0.z, sv); sv = fmaf(a0.w, a0.w, sv);
        sv = fmaf(a1.x, a1.x, sv); sv = fmaf(a1.y, a1.y, sv);
        sv = fmaf(a1.z, a1.z, sv); sv = fmaf(a1.w, a1.w, sv);
        sv = fmaf(a2.x, a2.x, sv); sv = fmaf(a2.y, a2.y, sv);
        sv = fmaf(a2.z, a2.z, sv); sv = fmaf(a2.w, a2.w, sv);
        sv = fmaf(a3.x, a3.x, sv); sv = fmaf(a3.y, a3.y, sv);
        sv = fmaf(a3.z, a3.z, sv); sv = fmaf(a3.w, a3.w, sv);
        const int idx = ((r & 1) << 8) | (r >> 1);
        ZA[0][idx] = make_uint4(pk(a0.x, a0.y), pk(a0.z, a0.w),
                                pk(a1.x, a1.y), pk(a1.z, a1.w));
        ZA[1][idx] = make_uint4(pk(a2.x, a2.y), pk(a2.z, a2.w),
                                pk(a3.x, a3.y), pk(a3.z, a3.w));
        Zs2p[idx] = LOG2E * sv;
    }
    // seam rings -> (BIGS, 1): matrix border; band-0 ring never written.
    // 4*64 = 256 float2 entries == blockDim
    ((float2*)&seam[0][0])[tt] = make_float2(BIGS, 1.0f);

    // ---- X rows for this lane (rows i0, i0+1) -> registers ----
    const int i0 = 128 * wv + 2 * t;
    unsigned Xu[2][8];
    float    xs2[2];
    const float* xp = X + ((size_t)n * TT + i0) * 16;
#pragma unroll
    for (int q = 0; q < 2; ++q) {
        const float4* xr = (const float4*)(xp + q * 16);
        const float4 a0 = xr[0], a1 = xr[1], a2 = xr[2], a3 = xr[3];
        float sv = 0.0f;
        sv = fmaf(a0.x, a0.x, sv); sv = fmaf(a0.y, a0.y, sv);
        sv = fmaf(a0.z, a0.z, sv); sv = fmaf(a0.w, a0.w, sv);
        sv = fmaf(a1.x, a1.x, sv); sv = fmaf(a1.y, a1.y, sv);
        sv = fmaf(a1.z, a1.z, sv); sv = fmaf(a1.w, a1.w, sv);
        sv = fmaf(a2.x, a2.x, sv); sv = fmaf(a2.y, a2.y, sv);
        sv = fmaf(a2.z, a2.z, sv); sv = fmaf(a2.w, a2.w, sv);
        sv = fmaf(a3.x, a3.x, sv); sv = fmaf(a3.y, a3.y, sv);
        sv = fmaf(a3.z, a3.z, sv); sv = fmaf(a3.w, a3.w, sv);
        xs2[q] = LOG2E * sv;
        Xu[q][0] = pk(a0.x, a0.y); Xu[q][1] = pk(a0.z, a0.w);
        Xu[q][2] = pk(a1.x, a1.y); Xu[q][3] = pk(a1.z, a1.w);
        Xu[q][4] = pk(a2.x, a2.y); Xu[q][5] = pk(a2.z, a2.w);
        Xu[q][6] = pk(a3.x, a3.y); Xu[q][7] = pk(a3.z, a3.w);
    }
    const float wgt = w[n];
    const float2* rKS = &seam[wv][0];
    __syncthreads();

    float RpK[2], RpS[2], poK, poS, bnK, bnS;
    float ddc[2];                    // dd for the CURRENT tick (pipelined)
    float2 smv[2];                   // seam prefetch slots (parity of tl+1)
    uint4 Zb[2][2];                  // Z-row prefetch slots (parity of tl+1)
    float zsb[2];
    RpK[0] = RpK[1] = BIGS; RpS[0] = RpS[1] = 1.0f;
    poK = BIGS; poS = 1.0f; bnK = BIGS; bnS = 1.0f;
    ddc[0] = ddc[1] = 0.0f;
    smv[0] = smv[1] = make_float2(BIGS, 1.0f);
    zsb[0] = zsb[1] = 0.0f;
    Zb[0][0] = Zb[0][1] = Zb[1][0] = Zb[1][1] = make_uint4(0, 0, 0, 0);

// q must equal ((tl)+1)&1 at each expansion (tb is even).
#define TICK(q, tl)                                                           \
    {                                                                         \
        const float unK = bnK, unS = bnS;                                     \
        const float2 sprev = smv[q];           /* ring[(tl+1)&63] */          \
        smv[q] = rKS[((tl) + 3) & 63];         /* for tick tl+2 */            \
        /* softmin on pipelined ddc -- all operands ready at tick start */    \
        const float l0K = RpK[0], l0S = RpS[0];                               \
        const float m0 = fminf(fminf(unK, l0K), poK);                         \
        const float s0 = exp2f(m0 - unK) * unS                                \
                       + exp2f(m0 - l0K) * l0S                                \
                       + exp2f(m0 - poK) * poS;                               \
        const float K0 = ddc[0] + m0;                                         \
        const float l1K = RpK[1], l1S = RpS[1];                               \
        const float m1 = fminf(fminf(K0, l1K), l0K);                          \
        const float s1 = exp2f(m1 - K0) * s0                                  \
                       + exp2f(m1 - l1K) * l1S                                \
                       + exp2f(m1 - l0K) * l0S;                               \
        const float K1 = ddc[1] + m1;                                         \
        const int j = (tl) - t;                                               \
        const bool ok = (j >= 0) && (j < 512);                                \
        RpK[0] = ok ? K0 : RpK[0];  RpS[0] = ok ? s0 : RpS[0];                \
        RpK[1] = ok ? K1 : RpK[1];  RpS[1] = ok ? s1 : RpS[1];                \
        if (ok && wv < 3 && t == 63) {                                        \
            seam[wv + 1][j & 63] = make_float2(RpK[1], RpS[1]);               \
        }                                                                     \
        poK = unK; poS = unS;                                                 \
        bnK = dppshr1(RpK[1], sprev.x);        /* boundary for tick tl+1 */   \
        bnS = dppshr1(RpS[1], sprev.y);                                       \
        /* ---- produce dd for tick tl+1 from Zb[q] = Z(tl+1); ---- */        \
        /* ---- refill Zb[q] <- Z(tl+3) (used at tick tl+2)     ---- */       \
        const uint4 z0 = Zb[q][0], z1 = Zb[q][1];                             \
        const float zz = zsb[q];                                              \
        {                                                                     \
            const int xn = ZROW((tl) + 3 - t);                                \
            Zb[q][0] = ZA[0][xn];                                             \
            Zb[q][1] = ZA[1][xn];                                             \
            zsb[q] = Zs2p[xn];                                                \
        }                                                                     \
        float a0 = 0.0f, b0 = 0.0f, a1 = 0.0f, b1 = 0.0f;                     \
        a0 = FDOT2(z0.x, Xu[0][0], a0); a0 = FDOT2(z0.y, Xu[0][1], a0);       \
        a0 = FDOT2(z0.z, Xu[0][2], a0); a0 = FDOT2(z0.w, Xu[0][3], a0);       \
        b0 = FDOT2(z1.x, Xu[0][4], b0); b0 = FDOT2(z1.y, Xu[0][5], b0);       \
        b0 = FDOT2(z1.z, Xu[0][6], b0); b0 = FDOT2(z1.w, Xu[0][7], b0);       \
        a1 = FDOT2(z0.x, Xu[1][0], a1); a1 = FDOT2(z0.y, Xu[1][1], a1);       \
        a1 = FDOT2(z0.z, Xu[1][2], a1); a1 = FDOT2(z0.w, Xu[1][3], a1);       \
        b1 = FDOT2(z1.x, Xu[1][4], b1); b1 = FDOT2(z1.y, Xu[1][5], b1);       \
        b1 = FDOT2(z1.z, Xu[1][6], b1); b1 = FDOT2(z1.w, Xu[1][7], b1);       \
        ddc[0] = fmaf(M2L, a0 + b0, xs2[0] + zz);                             \
        ddc[1] = fmaf(M2L, a1 + b1, xs2[1] + zz);                             \
    }

#define RENORM                                                                \
    {                                                                         \
        _Pragma("unroll")                                                     \
        for (int q = 0; q < 2; ++q) {                                         \
            const int e = (int)(__float_as_uint(RpS[q]) >> 23) - 127;         \
            RpS[q] = __uint_as_float(__float_as_uint(RpS[q])                  \
                                     - ((unsigned)e << 23));                  \
            RpK[q] -= (float)e;                                               \
        }                                                                     \
    }

#pragma unroll 1
    for (int s = 0; s < N_SS; ++s) {
        const int tb = P_SS * s - G_LAG * wv;
        if (tb >= 0 && tb <= 574) {
            if (tb == 0) {
                // activation: DP state + boundary + prefetch pipelines
                RpK[0] = RpK[1] = BIGS; RpS[0] = RpS[1] = 1.0f;
                poK = (wv == 0 && t == 0) ? 0.0f : BIGS; poS = 1.0f;  // corner
                const float2 r0 = rKS[0];
                bnK = r0.x; bnS = r0.y;   // un(tick0): lane0 real, rest masked
                smv[1] = rKS[1];          // sprev for tick 0
                smv[0] = rKS[2];          // sprev for tick 1
                // Z prefetch: tick0 consumes Zb[1]=Z(1); tick1 Zb[0]=Z(2)
                const int x1 = ZROW(1 - t);
                const int x2 = ZROW(2 - t);
                Zb[1][0] = ZA[0][x1]; Zb[1][1] = ZA[1][x1]; zsb[1] = Zs2p[x1];
                Zb[0][0] = ZA[0][x2]; Zb[0][1] = ZA[1][x2]; zsb[0] = Zs2p[x2];
                // dd for tick 0 directly from Z(0)
                const int x0 = ZROW(0 - t);
                const uint4 c0 = ZA[0][x0], c1 = ZA[1][x0];
                const float zz0 = Zs2p[x0];
                float a0 = 0.0f, b0 = 0.0f, a1 = 0.0f, b1 = 0.0f;
                a0 = FDOT2(c0.x, Xu[0][0], a0); a0 = FDOT2(c0.y, Xu[0][1], a0);
                a0 = FDOT2(c0.z, Xu[0][2], a0); a0 = FDOT2(c0.w, Xu[0][3], a0);
                b0 = FDOT2(c1.x, Xu[0][4], b0); b0 = FDOT2(c1.y, Xu[0][5], b0);
                b0 = FDOT2(c1.z, Xu[0][6], b0); b0 = FDOT2(c1.w, Xu[0][7], b0);
                a1 = FDOT2(c0.x, Xu[1][0], a1); a1 = FDOT2(c0.y, Xu[1][1], a1);
                a1 = FDOT2(c0.z, Xu[1][2], a1); a1 = FDOT2(c0.w, Xu[1][3], a1);
                b1 = FDOT2(c1.x, Xu[1][4], b1); b1 = FDOT2(c1.y, Xu[1][5], b1);
                b1 = FDOT2(c1.z, Xu[1][6], b1); b1 = FDOT2(c1.w, Xu[1][7], b1);
                ddc[0] = fmaf(M2L, a0 + b0, xs2[0] + zz0);
                ddc[1] = fmaf(M2L, a1 + b1, xs2[1] + zz0);
            }
            TICK(1, tb + 0)  TICK(0, tb + 1)  TICK(1, tb + 2)  TICK(0, tb + 3)
            TICK(1, tb + 4)  TICK(0, tb + 5)  TICK(1, tb + 6)  TICK(0, tb + 7)
            RENORM
            TICK(1, tb + 8)  TICK(0, tb + 9)  TICK(1, tb + 10) TICK(0, tb + 11)
            TICK(1, tb + 12) TICK(0, tb + 13) TICK(1, tb + 14) TICK(0, tb + 15)
            RENORM
        }
        __syncthreads();
    }
#undef TICK
#undef RENORM

    // band 3, lane 63, row 511 at tick 574 -> R(511,511) = K - log2(sm)
    if (wv == 3 && t == 63) {
        atomicAdd(out, wgt * (RpK[1] - log2f(RpS[1])) * LN2F);
    }
}

__global__ void k_zero(float* out) {
    if (threadIdx.x == 0) out[0] = 0.0f;
}

extern "C" void kernel_launch(void* const* d_in, const int* in_sizes, int n_in,
                              void* d_out, int out_size, void* d_ws, size_t ws_size,
                              hipStream_t stream) {
    const float* X = (const float*)d_in[0];   // (64, 512, 16) f32
    const float* w = (const float*)d_in[1];   // (64,) f32
    const float* Z = (const float*)d_in[2];   // (512, 16) f32
    float* out = (float*)d_out;               // scalar f32

    hipLaunchKernelGGL(k_zero, dim3(1), dim3(64), 0, stream, out);
    hipLaunchKernelGGL(k_fused, dim3(64), dim3(256), 0, stream, X, Z, w, out);
}

// Round 5
// 249.074 us; speedup vs baseline: 2.3728x; 1.0358x over previous
//
#include <hip/hip_runtime.h>

#define TT 512
#define BIGS 1.4426950408889634e10f   // BIG(1e10) * log2(e), scaled domain
#define LOG2E 1.4426950408889634f
#define M2L  (-2.0f * 1.4426950408889634f)
#define LN2F 0.69314718055994531f
#define P_SS 16                       // ticks per superstep (barrier period)
#define G_LAG 96                      // band lag (r14-verified margins)
#define N_SS 54                       // band3 last tick 574+288=862 -> s=53

typedef _Float16 h2 __attribute__((ext_vector_type(2)));

__device__ __forceinline__ unsigned pk(float a, float b) {
    h2 v; v.x = (_Float16)a; v.y = (_Float16)b;
    return __builtin_bit_cast(unsigned, v);
}

#if __has_builtin(__builtin_amdgcn_fdot2)
#define FDOT2(a, b, c) __builtin_amdgcn_fdot2(__builtin_bit_cast(h2, (a)), \
                                              __builtin_bit_cast(h2, (b)), (c), false)
#else
__device__ __forceinline__ float fdot2_sw(unsigned a, unsigned b, float c) {
    h2 ha = __builtin_bit_cast(h2, a), hb = __builtin_bit_cast(h2, b);
    return c + (float)ha.x * (float)hb.x + (float)ha.y * (float)hb.y;
}
#define FDOT2(a, b, c) fdot2_sw((a), (b), (c))
#endif

// permuted Z index, pure bitops (valid for any int j; wraps out-of-range j
// onto some valid row -- garbage rows only feed masked ticks)
#define ZROW(jv) (((((jv) & 1)) << 8) | ((((jv) >> 1)) & 255))

// lane-shift-up-by-1 via DPP wave_shr:1 (VALU) instead of ds_permute on the
// loop-carried path. Lane 0 takes `old` = seam value. Verified r13/r14.
__device__ __forceinline__ float dppshr1(float x, float old) {
#if __has_builtin(__builtin_amdgcn_update_dpp)
    return __builtin_bit_cast(float,
        __builtin_amdgcn_update_dpp(__builtin_bit_cast(int, old),
                                    __builtin_bit_cast(int, x),
                                    0x138 /*wave_shr:1*/, 0xF, 0xF, false));
#else
    const float v = __shfl_up(x, 1);
    return ((threadIdx.x & 63) == 0) ? old : v;
#endif
}

// ---------------------------------------------------------------------------
// Round 15 = r14 + BATCHED SEAM WRITES.
// Theory: the per-tick LDS seam write and the per-tick seam-ring prefetch
// read hit the SAME __shared__ array; alias analysis cannot disambiguate,
// so every tick's ds_read is ordered after that tick's ds_write -> ~120cy
// LDS latency exposed per tick (the invariant ~400cy stall that survived
// r11/r13/r14's content surgery).
// Fix: lane 63 accumulates its 8 seam entries per half-superstep in
// registers (float2 sk[8], statically indexed) and flushes them in ONE
// guarded block every 8 ticks; per-entry validity via branch-free address
// select into a dummy LDS slot. Read-after-write ordering now bites twice
// per superstep instead of 16x.
// Margins (re-proved): pair q flushed <= tick q+70, consumed at q+93 ->
// 23-tick margin > P_SS -> a barrier always separates write and read.
// Everything else byte-identical to r14 (absmax 0 verified).
// ---------------------------------------------------------------------------
__global__ __launch_bounds__(256, 1) void k_fused(const float* __restrict__ X,
                                                  const float* __restrict__ Z,
                                                  const float* __restrict__ w,
                                                  float* __restrict__ out) {
    const int tt = threadIdx.x;
    const int t  = tt & 63;          // lane
    const int wv = tt >> 6;          // wave = row band 0..3
    const int n  = blockIdx.x;       // sample

    __shared__ uint4  ZA[2][512];    // Z rows fp16-packed, permuted idx
    __shared__ float  Zs2p[512];     // LOG2E*|z|^2 at permuted idx
    __shared__ float2 seam[4][64];   // seam rings (K, sm); band0 = border
    __shared__ float2 dump2;         // sink for masked-out seam flushes

    // ---- stage Z into LDS: thread tt handles rows tt, tt+256 ----
#pragma unroll
    for (int h = 0; h < 2; ++h) {
        const int r = tt + h * 256;
        const float4* zp = (const float4*)(Z + (size_t)r * 16);
        const float4 a0 = zp[0], a1 = zp[1], a2 = zp[2], a3 = zp[3];
        float sv = 0.0f;
        sv = fmaf(a0.x, a0.x, sv); sv = fmaf(a0.y, a0.y, sv);
        sv = fmaf(a0.z, a0.z, sv); sv = fmaf(a0.w, a0.w, sv);
        sv = fmaf(a1.x, a1.x, sv); sv = fmaf(a1.y, a1.y, sv);
        sv = fmaf(a1.z, a1.z, sv); sv = fmaf(a1.w, a1.w, sv);
        sv = fmaf(a2.x, a2.x, sv); sv = fmaf(a2.y, a2.y, sv);
        sv = fmaf(a2.z, a2.z, sv); sv = fmaf(a2.w, a2.w, sv);
        sv = fmaf(a3.x, a3.x, sv); sv = fmaf(a3.y, a3.y, sv);
        sv = fmaf(a3.z, a3.z, sv); sv = fmaf(a3.w, a3.w, sv);
        const int idx = ((r & 1) << 8) | (r >> 1);
        ZA[0][idx] = make_uint4(pk(a0.x, a0.y), pk(a0.z, a0.w),
                                pk(a1.x, a1.y), pk(a1.z, a1.w));
        ZA[1][idx] = make_uint4(pk(a2.x, a2.y), pk(a2.z, a2.w),
                                pk(a3.x, a3.y), pk(a3.z, a3.w));
        Zs2p[idx] = LOG2E * sv;
    }
    // seam rings -> (BIGS, 1): matrix border; band-0 ring never written.
    ((float2*)&seam[0][0])[tt] = make_float2(BIGS, 1.0f);

    // ---- X rows for this lane (rows i0, i0+1) -> registers ----
    const int i0 = 128 * wv + 2 * t;
    unsigned Xu[2][8];
    float    xs2[2];
    const float* xp = X + ((size_t)n * TT + i0) * 16;
#pragma unroll
    for (int q = 0; q < 2; ++q) {
        const float4* xr = (const float4*)(xp + q * 16);
        const float4 a0 = xr[0], a1 = xr[1], a2 = xr[2], a3 = xr[3];
        float sv = 0.0f;
        sv = fmaf(a0.x, a0.x, sv); sv = fmaf(a0.y, a0.y, sv);
        sv = fmaf(a0.z, a0.z, sv); sv = fmaf(a0.w, a0.w, sv);
        sv = fmaf(a1.x, a1.x, sv); sv = fmaf(a1.y, a1.y, sv);
        sv = fmaf(a1.z, a1.z, sv); sv = fmaf(a1.w, a1.w, sv);
        sv = fmaf(a2.x, a2.x, sv); sv = fmaf(a2.y, a2.y, sv);
        sv = fmaf(a2.z, a2.z, sv); sv = fmaf(a2.w, a2.w, sv);
        sv = fmaf(a3.x, a3.x, sv); sv = fmaf(a3.y, a3.y, sv);
        sv = fmaf(a3.z, a3.z, sv); sv = fmaf(a3.w, a3.w, sv);
        xs2[q] = LOG2E * sv;
        Xu[q][0] = pk(a0.x, a0.y); Xu[q][1] = pk(a0.z, a0.w);
        Xu[q][2] = pk(a1.x, a1.y); Xu[q][3] = pk(a1.z, a1.w);
        Xu[q][4] = pk(a2.x, a2.y); Xu[q][5] = pk(a2.z, a2.w);
        Xu[q][6] = pk(a3.x, a3.y); Xu[q][7] = pk(a3.z, a3.w);
    }
    const float wgt = w[n];
    const float2* rKS = &seam[wv][0];
    float2* const wKS = (wv < 3) ? &seam[wv + 1][0] : &dump2;  // flush base
    __syncthreads();

    float RpK[2], RpS[2], poK, poS, bnK, bnS;
    float ddc[2];                    // dd for the CURRENT tick (pipelined)
    float2 smv[2];                   // seam prefetch slots (parity of tl+1)
    float2 sk[8];                    // seam write-combine (statically indexed)
    uint4 Zb[2][2];                  // Z-row prefetch slots (parity of tl+1)
    float zsb[2];
    RpK[0] = RpK[1] = BIGS; RpS[0] = RpS[1] = 1.0f;
    poK = BIGS; poS = 1.0f; bnK = BIGS; bnS = 1.0f;
    ddc[0] = ddc[1] = 0.0f;
    smv[0] = smv[1] = make_float2(BIGS, 1.0f);
    zsb[0] = zsb[1] = 0.0f;
    Zb[0][0] = Zb[0][1] = Zb[1][0] = Zb[1][1] = make_uint4(0, 0, 0, 0);
#pragma unroll
    for (int e = 0; e < 8; ++e) sk[e] = make_float2(BIGS, 1.0f);

// q must equal ((tl)+1)&1 at each expansion; k = (tl) - tb in [0,16).
#define TICK(q, k, tl)                                                        \
    {                                                                         \
        const float unK = bnK, unS = bnS;                                     \
        const float2 sprev = smv[q];           /* ring[(tl+1)&63] */          \
        smv[q] = rKS[((tl) + 3) & 63];         /* for tick tl+2 */            \
        /* softmin on pipelined ddc -- all operands ready at tick start */    \
        const float l0K = RpK[0], l0S = RpS[0];                               \
        const float m0 = fminf(fminf(unK, l0K), poK);                         \
        const float s0 = exp2f(m0 - unK) * unS                                \
                       + exp2f(m0 - l0K) * l0S                                \
                       + exp2f(m0 - poK) * poS;                               \
        const float K0 = ddc[0] + m0;                                         \
        const float l1K = RpK[1], l1S = RpS[1];                               \
        const float m1 = fminf(fminf(K0, l1K), l0K);                          \
        const float s1 = exp2f(m1 - K0) * s0                                  \
                       + exp2f(m1 - l1K) * l1S                                \
                       + exp2f(m1 - l0K) * l0S;                               \
        const float K1 = ddc[1] + m1;                                         \
        const int j = (tl) - t;                                               \
        const bool ok = (j >= 0) && (j < 512);                                \
        RpK[0] = ok ? K0 : RpK[0];  RpS[0] = ok ? s0 : RpS[0];                \
        RpK[1] = ok ? K1 : RpK[1];  RpS[1] = ok ? s1 : RpS[1];                \
        sk[(k) & 7] = make_float2(RpK[1], RpS[1]);   /* write-combine */      \
        poK = unK; poS = unS;                                                 \
        bnK = dppshr1(RpK[1], sprev.x);        /* boundary for tick tl+1 */   \
        bnS = dppshr1(RpS[1], sprev.y);                                       \
        /* ---- produce dd for tick tl+1 from Zb[q] = Z(tl+1); ---- */        \
        /* ---- refill Zb[q] <- Z(tl+3) (used at tick tl+2)     ---- */       \
        const uint4 z0 = Zb[q][0], z1 = Zb[q][1];                             \
        const float zz = zsb[q];                                              \
        {                                                                     \
            const int xn = ZROW((tl) + 3 - t);                                \
            Zb[q][0] = ZA[0][xn];                                             \
            Zb[q][1] = ZA[1][xn];                                             \
            zsb[q] = Zs2p[xn];                                                \
        }                                                                     \
        float a0 = 0.0f, b0 = 0.0f, a1 = 0.0f, b1 = 0.0f;                     \
        a0 = FDOT2(z0.x, Xu[0][0], a0); a0 = FDOT2(z0.y, Xu[0][1], a0);       \
        a0 = FDOT2(z0.z, Xu[0][2], a0); a0 = FDOT2(z0.w, Xu[0][3], a0);       \
        b0 = FDOT2(z1.x, Xu[0][4], b0); b0 = FDOT2(z1.y, Xu[0][5], b0);       \
        b0 = FDOT2(z1.z, Xu[0][6], b0); b0 = FDOT2(z1.w, Xu[0][7], b0);       \
        a1 = FDOT2(z0.x, Xu[1][0], a1); a1 = FDOT2(z0.y, Xu[1][1], a1);       \
        a1 = FDOT2(z0.z, Xu[1][2], a1); a1 = FDOT2(z0.w, Xu[1][3], a1);       \
        b1 = FDOT2(z1.x, Xu[1][4], b1); b1 = FDOT2(z1.y, Xu[1][5], b1);       \
        b1 = FDOT2(z1.z, Xu[1][6], b1); b1 = FDOT2(z1.w, Xu[1][7], b1);       \
        ddc[0] = fmaf(M2L, a0 + b0, xs2[0] + zz);                             \
        ddc[1] = fmaf(M2L, a1 + b1, xs2[1] + zz);                             \
    }

// flush sk[0..7] (seam entries for ticks tb+g*8 .. tb+g*8+7) in one block.
// entry e covers column j = tb + g*8 + e - 63 (lane 63); invalid entries
// are steered to &dump2 (branch-free address select).
#define FLUSH(g)                                                              \
    if (t == 63 && wv < 3) {                                                  \
        const int jb = tb + (g) * 8 - 63;                                     \
        _Pragma("unroll")                                                     \
        for (int e = 0; e < 8; ++e) {                                         \
            const int je = jb + e;                                            \
            const bool oke = (je >= 0) && (je < 512);                         \
            float2* const dst = oke ? (wKS + (je & 63)) : &dump2;             \
            *dst = sk[e];                                                     \
        }                                                                     \
    }

#define RENORM                                                                \
    {                                                                         \
        _Pragma("unroll")                                                     \
        for (int q = 0; q < 2; ++q) {                                         \
            const int e = (int)(__float_as_uint(RpS[q]) >> 23) - 127;         \
            RpS[q] = __uint_as_float(__float_as_uint(RpS[q])                  \
                                     - ((unsigned)e << 23));                  \
            RpK[q] -= (float)e;                                               \
        }                                                                     \
    }

#pragma unroll 1
    for (int s = 0; s < N_SS; ++s) {
        const int tb = P_SS * s - G_LAG * wv;
        if (tb >= 0 && tb <= 574) {
            if (tb == 0) {
                // activation: DP state + boundary + prefetch pipelines
                RpK[0] = RpK[1] = BIGS; RpS[0] = RpS[1] = 1.0f;
                poK = (wv == 0 && t == 0) ? 0.0f : BIGS; poS = 1.0f;  // corner
                const float2 r0 = rKS[0];
                bnK = r0.x; bnS = r0.y;   // un(tick0): lane0 real, rest masked
                smv[1] = rKS[1];          // sprev for tick 0
                smv[0] = rKS[2];          // sprev for tick 1
                // Z prefetch: tick0 consumes Zb[1]=Z(1); tick1 Zb[0]=Z(2)
                const int x1 = ZROW(1 - t);
                const int x2 = ZROW(2 - t);
                Zb[1][0] = ZA[0][x1]; Zb[1][1] = ZA[1][x1]; zsb[1] = Zs2p[x1];
                Zb[0][0] = ZA[0][x2]; Zb[0][1] = ZA[1][x2]; zsb[0] = Zs2p[x2];
                // dd for tick 0 directly from Z(0)
                const int x0 = ZROW(0 - t);
                const uint4 c0 = ZA[0][x0], c1 = ZA[1][x0];
                const float zz0 = Zs2p[x0];
                float a0 = 0.0f, b0 = 0.0f, a1 = 0.0f, b1 = 0.0f;
                a0 = FDOT2(c0.x, Xu[0][0], a0); a0 = FDOT2(c0.y, Xu[0][1], a0);
                a0 = FDOT2(c0.z, Xu[0][2], a0); a0 = FDOT2(c0.w, Xu[0][3], a0);
                b0 = FDOT2(c1.x, Xu[0][4], b0); b0 = FDOT2(c1.y, Xu[0][5], b0);
                b0 = FDOT2(c1.z, Xu[0][6], b0); b0 = FDOT2(c1.w, Xu[0][7], b0);
                a1 = FDOT2(c0.x, Xu[1][0], a1); a1 = FDOT2(c0.y, Xu[1][1], a1);
                a1 = FDOT2(c0.z, Xu[1][2], a1); a1 = FDOT2(c0.w, Xu[1][3], a1);
                b1 = FDOT2(c1.x, Xu[1][4], b1); b1 = FDOT2(c1.y, Xu[1][5], b1);
                b1 = FDOT2(c1.z, Xu[1][6], b1); b1 = FDOT2(c1.w, Xu[1][7], b1);
                ddc[0] = fmaf(M2L, a0 + b0, xs2[0] + zz0);
                ddc[1] = fmaf(M2L, a1 + b1, xs2[1] + zz0);
            }
            TICK(1, 0, tb + 0)   TICK(0, 1, tb + 1)
            TICK(1, 2, tb + 2)   TICK(0, 3, tb + 3)
            TICK(1, 4, tb + 4)   TICK(0, 5, tb + 5)
            TICK(1, 6, tb + 6)   TICK(0, 7, tb + 7)
            RENORM
            FLUSH(0)
            TICK(1, 8, tb + 8)   TICK(0, 9, tb + 9)
            TICK(1, 10, tb + 10) TICK(0, 11, tb + 11)
            TICK(1, 12, tb + 12) TICK(0, 13, tb + 13)
            TICK(1, 14, tb + 14) TICK(0, 15, tb + 15)
            RENORM
            FLUSH(1)
        }
        __syncthreads();
    }
#undef TICK
#undef FLUSH
#undef RENORM

    // band 3, lane 63, row 511 at tick 574 -> R(511,511) = K - log2(sm)
    if (wv == 3 && t == 63) {
        atomicAdd(out, wgt * (RpK[1] - log2f(RpS[1])) * LN2F);
    }
}

__global__ void k_zero(float* out) {
    if (threadIdx.x == 0) out[0] = 0.0f;
}

extern "C" void kernel_launch(void* const* d_in, const int* in_sizes, int n_in,
                              void* d_out, int out_size, void* d_ws, size_t ws_size,
                              hipStream_t stream) {
    const float* X = (const float*)d_in[0];   // (64, 512, 16) f32
    const float* w = (const float*)d_in[1];   // (64,) f32
    const float* Z = (const float*)d_in[2];   // (512, 16) f32
    float* out = (float*)d_out;               // scalar f32

    hipLaunchKernelGGL(k_zero, dim3(1), dim3(64), 0, stream, out);
    hipLaunchKernelGGL(k_fused, dim3(64), dim3(256), 0, stream, X, Z, w, out);
}

// Round 6
// 178.692 us; speedup vs baseline: 3.3074x; 1.3939x over previous
//
#include <hip/hip_runtime.h>

#define TT 512
#define BIGS 1.4426950408889634e10f   // BIG(1e10) * log2(e), scaled domain
#define LOG2E 1.4426950408889634f
#define M2L  (-2.0f * 1.4426950408889634f)
#define LN2F 0.69314718055994531f
#define P_SS 16                       // ticks per superstep (barrier period)
#define G_LAG 96                      // band lag (r14-verified margins)
#define N_SS 54                       // band3 last tick 574+288=862 -> s=53
#define RSTR 130                      // ring row stride (words); 128 slots + pad
                                      // read bank = (t + col) % 32 -> 2-way (free)

typedef _Float16 h2 __attribute__((ext_vector_type(2)));

__device__ __forceinline__ unsigned pk(float a, float b) {
    h2 v; v.x = (_Float16)a; v.y = (_Float16)b;
    return __builtin_bit_cast(unsigned, v);
}

#if __has_builtin(__builtin_amdgcn_fdot2)
#define FDOT2(a, b, c) __builtin_amdgcn_fdot2(__builtin_bit_cast(h2, (a)), \
                                              __builtin_bit_cast(h2, (b)), (c), false)
#else
__device__ __forceinline__ float fdot2_sw(unsigned a, unsigned b, float c) {
    h2 ha = __builtin_bit_cast(h2, a), hb = __builtin_bit_cast(h2, b);
    return c + (float)ha.x * (float)hb.x + (float)ha.y * (float)hb.y;
}
#define FDOT2(a, b, c) fdot2_sw((a), (b), (c))
#endif

// raw v_exp_f32 (bypass any OCML wrapper; args here are always finite)
#if __has_builtin(__builtin_amdgcn_exp2f)
#define EXP2F(x) __builtin_amdgcn_exp2f(x)
#else
#define EXP2F(x) exp2f(x)
#endif

// permuted Z index, pure bitops (valid for any int j; wraps out-of-range j
// onto some valid row -- garbage rows only feed masked ticks)
#define ZROW(jv) (((((jv) & 1)) << 8) | ((((jv) >> 1)) & 255))

// lane-shift-up-by-1 via DPP wave_shr:1 (VALU) instead of ds_permute on the
// loop-carried path. Lane 0 takes `old` = seam value. Verified r13/r14.
__device__ __forceinline__ float dppshr1(float x, float old) {
#if __has_builtin(__builtin_amdgcn_update_dpp)
    return __builtin_bit_cast(float,
        __builtin_amdgcn_update_dpp(__builtin_bit_cast(int, old),
                                    __builtin_bit_cast(int, x),
                                    0x138 /*wave_shr:1*/, 0xF, 0xF, false));
#else
    const float v = __shfl_up(x, 1);
    return ((threadIdx.x & 63) == 0) ? old : v;
#endif
}

// ---------------------------------------------------------------------------
// Round 16: PRODUCER/CONSUMER WAVE SPECIALIZATION.
// Evidence: r12 proved independent waves on a SIMD fill each other's stalls
// (600 -> ~395 cy/slot) but idled CUs; r11 proved the ring machinery correct
// but ran production serial with the DP (adding issue to the critical wave).
// This round combines them: 8 waves/block on all 64 blocks --
//   waves 0..3 : DP bands (r14's verified schedule, 864 ticks), tick slimmed
//                to {ring b32 read + seam read/write + softmin + DPP}
//   waves 4..7 : producers; wave 4+b computes band b's fp16-packed dd pairs
//                (16 FDOT2 per col pair) into ring[b][t][.] one 16-col tile
//                per superstep, one superstep ahead of consumption.
// Ring: 128 cols (8 tiles of 16), slot = col & 127 (pow2, no magic mod).
// Margins (proved): tile T produced at s=6b+T-2, first consumed s=6b+T-1
// (barrier-ordered); overwrites tile T-8 whose last valid read is s=6b+T-4.
// Band 0's tiles 0,1 produced in a pre-loop step behind an extra barrier.
// Also: exp2f -> __builtin_amdgcn_exp2f (6 per tick; bypass OCML wrapper).
// DP per-cell math, renorm, masks, seam, activation identical to r14
// (absmax 0); dd is fp16-rounded as in r11 (absmax 0).
// ---------------------------------------------------------------------------
__global__ __launch_bounds__(512, 1) void k_fused(const float* __restrict__ X,
                                                  const float* __restrict__ Z,
                                                  const float* __restrict__ w,
                                                  float* __restrict__ out) {
    const int tt = threadIdx.x;
    const int t  = tt & 63;          // lane
    const int wv = tt >> 6;          // wave 0..7
    const int bd = (wv < 4) ? wv : (wv - 4);   // band this wave serves
    const int n  = blockIdx.x;       // sample

    __shared__ uint4    ZA[2][512];  // Z rows fp16-packed, permuted idx
    __shared__ float    Zs2p[512];   // LOG2E*|z|^2 at permuted idx
    __shared__ float2   seam[4][64]; // seam rings (K, sm); band0 = border
    __shared__ unsigned ring[4][64][RSTR];  // fp16x2 dd pairs, slot = col&127

    // ---- stage Z into LDS: thread tt handles row tt ----
    {
        const int r = tt;
        const float4* zp = (const float4*)(Z + (size_t)r * 16);
        const float4 a0 = zp[0], a1 = zp[1], a2 = zp[2], a3 = zp[3];
        float sv = 0.0f;
        sv = fmaf(a0.x, a0.x, sv); sv = fmaf(a0.y, a0.y, sv);
        sv = fmaf(a0.z, a0.z, sv); sv = fmaf(a0.w, a0.w, sv);
        sv = fmaf(a1.x, a1.x, sv); sv = fmaf(a1.y, a1.y, sv);
        sv = fmaf(a1.z, a1.z, sv); sv = fmaf(a1.w, a1.w, sv);
        sv = fmaf(a2.x, a2.x, sv); sv = fmaf(a2.y, a2.y, sv);
        sv = fmaf(a2.z, a2.z, sv); sv = fmaf(a2.w, a2.w, sv);
        sv = fmaf(a3.x, a3.x, sv); sv = fmaf(a3.y, a3.y, sv);
        sv = fmaf(a3.z, a3.z, sv); sv = fmaf(a3.w, a3.w, sv);
        const int idx = ((r & 1) << 8) | (r >> 1);
        ZA[0][idx] = make_uint4(pk(a0.x, a0.y), pk(a0.z, a0.w),
                                pk(a1.x, a1.y), pk(a1.z, a1.w));
        ZA[1][idx] = make_uint4(pk(a2.x, a2.y), pk(a2.z, a2.w),
                                pk(a3.x, a3.y), pk(a3.z, a3.w));
        Zs2p[idx] = LOG2E * sv;
    }
    // seam rings -> (BIGS, 1): matrix border; band-0 ring never written.
    if (tt < 256) ((float2*)&seam[0][0])[tt] = make_float2(BIGS, 1.0f);

    // ---- X rows for band bd, lane t (rows i0, i0+1) -> registers ----
    // (both the DP wave and its producer load the same rows)
    const int i0 = 128 * bd + 2 * t;
    unsigned Xu[2][8];
    float    xs2[2];
    const float* xp = X + ((size_t)n * TT + i0) * 16;
#pragma unroll
    for (int q = 0; q < 2; ++q) {
        const float4* xr = (const float4*)(xp + q * 16);
        const float4 a0 = xr[0], a1 = xr[1], a2 = xr[2], a3 = xr[3];
        float sv = 0.0f;
        sv = fmaf(a0.x, a0.x, sv); sv = fmaf(a0.y, a0.y, sv);
        sv = fmaf(a0.z, a0.z, sv); sv = fmaf(a0.w, a0.w, sv);
        sv = fmaf(a1.x, a1.x, sv); sv = fmaf(a1.y, a1.y, sv);
        sv = fmaf(a1.z, a1.z, sv); sv = fmaf(a1.w, a1.w, sv);
        sv = fmaf(a2.x, a2.x, sv); sv = fmaf(a2.y, a2.y, sv);
        sv = fmaf(a2.z, a2.z, sv); sv = fmaf(a2.w, a2.w, sv);
        sv = fmaf(a3.x, a3.x, sv); sv = fmaf(a3.y, a3.y, sv);
        sv = fmaf(a3.z, a3.z, sv); sv = fmaf(a3.w, a3.w, sv);
        xs2[q] = LOG2E * sv;
        Xu[q][0] = pk(a0.x, a0.y); Xu[q][1] = pk(a0.z, a0.w);
        Xu[q][2] = pk(a1.x, a1.y); Xu[q][3] = pk(a1.z, a1.w);
        Xu[q][4] = pk(a2.x, a2.y); Xu[q][5] = pk(a2.z, a2.w);
        Xu[q][6] = pk(a3.x, a3.y); Xu[q][7] = pk(a3.z, a3.w);
    }
    const float wgt = w[n];
    const float2* rKS = &seam[bd][0];
    unsigned* const rg = &ring[bd][t][0];
    __syncthreads();

    // producer: fp16-packed dd pair for cols [16T, 16T+15] of this lane's rows
#define PRODUCE(Tv)                                                           \
    {                                                                         \
        const int base_ = (Tv) << 4;                                          \
        const int wb_ = base_ & 127;                                          \
        _Pragma("unroll 4")                                                   \
        for (int cc = 0; cc < 16; ++cc) {                                     \
            const int zr = ZROW(base_ + cc);       /* wave-uniform */         \
            const uint4 z0 = ZA[0][zr], z1 = ZA[1][zr];                       \
            const float zz = Zs2p[zr];                                        \
            float a0 = 0.0f, b0 = 0.0f, a1 = 0.0f, b1 = 0.0f;                 \
            a0 = FDOT2(z0.x, Xu[0][0], a0); a0 = FDOT2(z0.y, Xu[0][1], a0);   \
            a0 = FDOT2(z0.z, Xu[0][2], a0); a0 = FDOT2(z0.w, Xu[0][3], a0);   \
            b0 = FDOT2(z1.x, Xu[0][4], b0); b0 = FDOT2(z1.y, Xu[0][5], b0);   \
            b0 = FDOT2(z1.z, Xu[0][6], b0); b0 = FDOT2(z1.w, Xu[0][7], b0);   \
            a1 = FDOT2(z0.x, Xu[1][0], a1); a1 = FDOT2(z0.y, Xu[1][1], a1);   \
            a1 = FDOT2(z0.z, Xu[1][2], a1); a1 = FDOT2(z0.w, Xu[1][3], a1);   \
            b1 = FDOT2(z1.x, Xu[1][4], b1); b1 = FDOT2(z1.y, Xu[1][5], b1);   \
            b1 = FDOT2(z1.z, Xu[1][6], b1); b1 = FDOT2(z1.w, Xu[1][7], b1);   \
            const float dd0 = fmaf(M2L, a0 + b0, xs2[0] + zz);                \
            const float dd1 = fmaf(M2L, a1 + b1, xs2[1] + zz);                \
            rg[wb_ + cc] = pk(dd0, dd1);                                      \
        }                                                                     \
    }

    // pre-loop: band 0's tiles 0,1 (consumed at s=0) behind one barrier
    if (wv >= 4 && bd == 0) { PRODUCE(0) PRODUCE(1) }
    __syncthreads();

    // ---- DP state (producers carry these dead) ----
    float RpK[2], RpS[2], poK, poS, bnK, bnS;
    float2 smv[2];                   // seam prefetch slots (parity of tl+1)
    unsigned rv[2];                  // ring prefetch slots (parity of tl)
    RpK[0] = RpK[1] = BIGS; RpS[0] = RpS[1] = 1.0f;
    poK = BIGS; poS = 1.0f; bnK = BIGS; bnS = 1.0f;
    smv[0] = smv[1] = make_float2(BIGS, 1.0f);
    rv[0] = rv[1] = 0u;

// q must equal (tl)&1 at each expansion (tb is even).
#define TICK(q, tl)                                                           \
    {                                                                         \
        const float unK = bnK, unS = bnS;                                     \
        const float2 sprev = smv[q];           /* ring[(tl+1)&63] */          \
        smv[q] = rKS[((tl) + 3) & 63];         /* for tick tl+2 */            \
        const h2 dh = __builtin_bit_cast(h2, rv[q]);                          \
        rv[q] = rg[((unsigned)((tl) + 2 - t)) & 127];  /* for tick tl+2 */    \
        const float dd0 = (float)dh.x;                                        \
        const float dd1 = (float)dh.y;                                        \
        const float l0K = RpK[0], l0S = RpS[0];                               \
        const float m0 = fminf(fminf(unK, l0K), poK);                         \
        const float s0 = EXP2F(m0 - unK) * unS                                \
                       + EXP2F(m0 - l0K) * l0S                                \
                       + EXP2F(m0 - poK) * poS;                               \
        const float K0 = dd0 + m0;                                            \
        const float l1K = RpK[1], l1S = RpS[1];                               \
        const float m1 = fminf(fminf(K0, l1K), l0K);                          \
        const float s1 = EXP2F(m1 - K0) * s0                                  \
                       + EXP2F(m1 - l1K) * l1S                                \
                       + EXP2F(m1 - l0K) * l0S;                               \
        const float K1 = dd1 + m1;                                            \
        const int j = (tl) - t;                                               \
        const bool ok = (j >= 0) && (j < 512);                                \
        RpK[0] = ok ? K0 : RpK[0];  RpS[0] = ok ? s0 : RpS[0];                \
        RpK[1] = ok ? K1 : RpK[1];  RpS[1] = ok ? s1 : RpS[1];                \
        if (ok && bd < 3 && t == 63) {                                        \
            seam[bd + 1][j & 63] = make_float2(RpK[1], RpS[1]);               \
        }                                                                     \
        poK = unK; poS = unS;                                                 \
        bnK = dppshr1(RpK[1], sprev.x);        /* boundary for tick tl+1 */   \
        bnS = dppshr1(RpS[1], sprev.y);                                       \
    }

#define RENORM                                                                \
    {                                                                         \
        _Pragma("unroll")                                                     \
        for (int q = 0; q < 2; ++q) {                                         \
            const int e = (int)(__float_as_uint(RpS[q]) >> 23) - 127;         \
            RpS[q] = __uint_as_float(__float_as_uint(RpS[q])                  \
                                     - ((unsigned)e << 23));                  \
            RpK[q] -= (float)e;                                               \
        }                                                                     \
    }

#pragma unroll 1
    for (int s = 0; s < N_SS; ++s) {
        if (wv >= 4) {
            // -------- producer wave: one 16-col tile, one superstep ahead --
            const int T = s - 6 * bd + 2;
            if (T >= 0 && T <= 31) PRODUCE(T)
        } else {
            // -------- DP wave: 16 ticks of band bd --------
            const int tb = P_SS * s - G_LAG * bd;
            if (tb >= 0 && tb <= 574) {
                if (tb == 0) {
                    // activation: DP state + boundary + prefetch pipelines
                    RpK[0] = RpK[1] = BIGS; RpS[0] = RpS[1] = 1.0f;
                    poK = (bd == 0 && t == 0) ? 0.0f : BIGS; poS = 1.0f;
                    const float2 r0 = rKS[0];
                    bnK = r0.x; bnS = r0.y;   // un(tick0)
                    smv[1] = rKS[1];          // sprev for tick 0
                    smv[0] = rKS[2];          // sprev for tick 1
                    rv[0] = rg[((unsigned)(0 - t)) & 127];   // col 0-t (tick 0)
                    rv[1] = rg[((unsigned)(1 - t)) & 127];   // col 1-t (tick 1)
                }
                TICK(0, tb + 0)  TICK(1, tb + 1)  TICK(0, tb + 2)  TICK(1, tb + 3)
                TICK(0, tb + 4)  TICK(1, tb + 5)  TICK(0, tb + 6)  TICK(1, tb + 7)
                RENORM
                TICK(0, tb + 8)  TICK(1, tb + 9)  TICK(0, tb + 10) TICK(1, tb + 11)
                TICK(0, tb + 12) TICK(1, tb + 13) TICK(0, tb + 14) TICK(1, tb + 15)
                RENORM
            }
        }
        __syncthreads();
    }
#undef TICK
#undef RENORM
#undef PRODUCE

    // band 3, lane 63, row 511 at tick 574 -> R(511,511) = K - log2(sm)
    if (wv == 3 && t == 63) {
        atomicAdd(out, wgt * (RpK[1] - log2f(RpS[1])) * LN2F);
    }
}

__global__ void k_zero(float* out) {
    if (threadIdx.x == 0) out[0] = 0.0f;
}

extern "C" void kernel_launch(void* const* d_in, const int* in_sizes, int n_in,
                              void* d_out, int out_size, void* d_ws, size_t ws_size,
                              hipStream_t stream) {
    const float* X = (const float*)d_in[0];   // (64, 512, 16) f32
    const float* w = (const float*)d_in[1];   // (64,) f32
    const float* Z = (const float*)d_in[2];   // (512, 16) f32
    float* out = (float*)d_out;               // scalar f32

    hipLaunchKernelGGL(k_zero, dim3(1), dim3(64), 0, stream, out);
    hipLaunchKernelGGL(k_fused, dim3(64), dim3(512), 0, stream, X, Z, w, out);
}

// Round 7
// 171.762 us; speedup vs baseline: 3.4408x; 1.0403x over previous
//
#include <hip/hip_runtime.h>

#define TT 512
#define BIGS 1.4426950408889634e10f   // BIG(1e10) * log2(e), scaled domain
#define LOG2E 1.4426950408889634f
#define M2L  (-2.0f * 1.4426950408889634f)
#define LN2F 0.69314718055994531f
#define P_SS 16                       // ticks per superstep (barrier period)
#define G_LAG 80                      // band lag (margins re-proved for seam-read@c-1)
#define N_SS 51                       // band3 last tick 574+240=814 -> s=50
#define RSTR 130                      // ring row stride (words); 128 slots + pad

typedef _Float16 h2 __attribute__((ext_vector_type(2)));

__device__ __forceinline__ unsigned pk(float a, float b) {
    h2 v; v.x = (_Float16)a; v.y = (_Float16)b;
    return __builtin_bit_cast(unsigned, v);
}

#if __has_builtin(__builtin_amdgcn_fdot2)
#define FDOT2(a, b, c) __builtin_amdgcn_fdot2(__builtin_bit_cast(h2, (a)), \
                                              __builtin_bit_cast(h2, (b)), (c), false)
#else
__device__ __forceinline__ float fdot2_sw(unsigned a, unsigned b, float c) {
    h2 ha = __builtin_bit_cast(h2, a), hb = __builtin_bit_cast(h2, b);
    return c + (float)ha.x * (float)hb.x + (float)ha.y * (float)hb.y;
}
#define FDOT2(a, b, c) fdot2_sw((a), (b), (c))
#endif

#if __has_builtin(__builtin_amdgcn_exp2f)
#define EXP2F(x) __builtin_amdgcn_exp2f(x)
#else
#define EXP2F(x) exp2f(x)
#endif

// permuted Z index, pure bitops (valid for any int j; wraps out-of-range j
// onto some valid row -- garbage rows only feed masked ticks)
#define ZROW(jv) (((((jv) & 1)) << 8) | ((((jv) >> 1)) & 255))

// lane-shift-up-by-1 via DPP wave_shr:1 (VALU) on the loop-carried path.
// Lane 0 takes `old` = seam value. Verified r13/r14/r16.
__device__ __forceinline__ float dppshr1(float x, float old) {
#if __has_builtin(__builtin_amdgcn_update_dpp)
    return __builtin_bit_cast(float,
        __builtin_amdgcn_update_dpp(__builtin_bit_cast(int, old),
                                    __builtin_bit_cast(int, x),
                                    0x138 /*wave_shr:1*/, 0xF, 0xF, false));
#else
    const float v = __shfl_up(x, 1);
    return ((threadIdx.x & 63) == 0) ? old : v;
#endif
}

// ---------------------------------------------------------------------------
// Round 17 = r16 (producer/consumer, verified 125us kernel) + three trims:
//  1. G_LAG 96->80 (-48 ticks): seam now read IN-TICK at ring[(tl+1)&63]
//     (read tick c-1). Margin proof: producer band b writes seam col c at
//     global c+63+80b; consumer reads at c+79+80b = +16 ticks = same
//     superstep position, NEXT superstep -> barrier always between. Ring
//     dd pacing moved to T = s - 5*bd + 2 (produced 2 ss before first read
//     at T-1+5bd; overwrites tile T-8 last read at T-4+5bd: 2-ss margin).
//  2. Interior-superstep specialization: tb in [64,496] (28/36 active ss)
//     has all lanes/ticks valid -> `ok` masks compile-time folded away.
//  3. s_setprio(1) around the DP tick block (T5: role-split now exists;
//     producers at prio 0 fill DP stall slots preferentially).
// DP per-cell math, renorm, DPP boundary, activation identical to r16
// (absmax 0 verified).
// ---------------------------------------------------------------------------
__global__ __launch_bounds__(512, 1) void k_fused(const float* __restrict__ X,
                                                  const float* __restrict__ Z,
                                                  const float* __restrict__ w,
                                                  float* __restrict__ out) {
    const int tt = threadIdx.x;
    const int t  = tt & 63;          // lane
    const int wv = tt >> 6;          // wave 0..7
    const int bd = (wv < 4) ? wv : (wv - 4);   // band this wave serves
    const int n  = blockIdx.x;       // sample

    __shared__ uint4    ZA[2][512];  // Z rows fp16-packed, permuted idx
    __shared__ float    Zs2p[512];   // LOG2E*|z|^2 at permuted idx
    __shared__ float2   seam[4][64]; // seam rings (K, sm); band0 = border
    __shared__ unsigned ring[4][64][RSTR];  // fp16x2 dd pairs, slot = col&127

    // ---- stage Z into LDS: thread tt handles row tt ----
    {
        const int r = tt;
        const float4* zp = (const float4*)(Z + (size_t)r * 16);
        const float4 a0 = zp[0], a1 = zp[1], a2 = zp[2], a3 = zp[3];
        float sv = 0.0f;
        sv = fmaf(a0.x, a0.x, sv); sv = fmaf(a0.y, a0.y, sv);
        sv = fmaf(a0.z, a0.z, sv); sv = fmaf(a0.w, a0.w, sv);
        sv = fmaf(a1.x, a1.x, sv); sv = fmaf(a1.y, a1.y, sv);
        sv = fmaf(a1.z, a1.z, sv); sv = fmaf(a1.w, a1.w, sv);
        sv = fmaf(a2.x, a2.x, sv); sv = fmaf(a2.y, a2.y, sv);
        sv = fmaf(a2.z, a2.z, sv); sv = fmaf(a2.w, a2.w, sv);
        sv = fmaf(a3.x, a3.x, sv); sv = fmaf(a3.y, a3.y, sv);
        sv = fmaf(a3.z, a3.z, sv); sv = fmaf(a3.w, a3.w, sv);
        const int idx = ((r & 1) << 8) | (r >> 1);
        ZA[0][idx] = make_uint4(pk(a0.x, a0.y), pk(a0.z, a0.w),
                                pk(a1.x, a1.y), pk(a1.z, a1.w));
        ZA[1][idx] = make_uint4(pk(a2.x, a2.y), pk(a2.z, a2.w),
                                pk(a3.x, a3.y), pk(a3.z, a3.w));
        Zs2p[idx] = LOG2E * sv;
    }
    // seam rings -> (BIGS, 1): matrix border; band-0 ring never written.
    if (tt < 256) ((float2*)&seam[0][0])[tt] = make_float2(BIGS, 1.0f);

    // ---- X rows for band bd, lane t (rows i0, i0+1) -> registers ----
    const int i0 = 128 * bd + 2 * t;
    unsigned Xu[2][8];
    float    xs2[2];
    const float* xp = X + ((size_t)n * TT + i0) * 16;
#pragma unroll
    for (int q = 0; q < 2; ++q) {
        const float4* xr = (const float4*)(xp + q * 16);
        const float4 a0 = xr[0], a1 = xr[1], a2 = xr[2], a3 = xr[3];
        float sv = 0.0f;
        sv = fmaf(a0.x, a0.x, sv); sv = fmaf(a0.y, a0.y, sv);
        sv = fmaf(a0.z, a0.z, sv); sv = fmaf(a0.w, a0.w, sv);
        sv = fmaf(a1.x, a1.x, sv); sv = fmaf(a1.y, a1.y, sv);
        sv = fmaf(a1.z, a1.z, sv); sv = fmaf(a1.w, a1.w, sv);
        sv = fmaf(a2.x, a2.x, sv); sv = fmaf(a2.y, a2.y, sv);
        sv = fmaf(a2.z, a2.z, sv); sv = fmaf(a2.w, a2.w, sv);
        sv = fmaf(a3.x, a3.x, sv); sv = fmaf(a3.y, a3.y, sv);
        sv = fmaf(a3.z, a3.z, sv); sv = fmaf(a3.w, a3.w, sv);
        xs2[q] = LOG2E * sv;
        Xu[q][0] = pk(a0.x, a0.y); Xu[q][1] = pk(a0.z, a0.w);
        Xu[q][2] = pk(a1.x, a1.y); Xu[q][3] = pk(a1.z, a1.w);
        Xu[q][4] = pk(a2.x, a2.y); Xu[q][5] = pk(a2.z, a2.w);
        Xu[q][6] = pk(a3.x, a3.y); Xu[q][7] = pk(a3.z, a3.w);
    }
    const float wgt = w[n];
    const float2* rKS = &seam[bd][0];
    unsigned* const rg = &ring[bd][t][0];
    __syncthreads();

    // producer: fp16-packed dd pair for cols [16T, 16T+15] of this lane's rows
#define PRODUCE(Tv)                                                           \
    {                                                                         \
        const int base_ = (Tv) << 4;                                          \
        const int wb_ = base_ & 127;                                          \
        _Pragma("unroll 4")                                                   \
        for (int cc = 0; cc < 16; ++cc) {                                     \
            const int zr = ZROW(base_ + cc);       /* wave-uniform */         \
            const uint4 z0 = ZA[0][zr], z1 = ZA[1][zr];                       \
            const float zz = Zs2p[zr];                                        \
            float a0 = 0.0f, b0 = 0.0f, a1 = 0.0f, b1 = 0.0f;                 \
            a0 = FDOT2(z0.x, Xu[0][0], a0); a0 = FDOT2(z0.y, Xu[0][1], a0);   \
            a0 = FDOT2(z0.z, Xu[0][2], a0); a0 = FDOT2(z0.w, Xu[0][3], a0);   \
            b0 = FDOT2(z1.x, Xu[0][4], b0); b0 = FDOT2(z1.y, Xu[0][5], b0);   \
            b0 = FDOT2(z1.z, Xu[0][6], b0); b0 = FDOT2(z1.w, Xu[0][7], b0);   \
            a1 = FDOT2(z0.x, Xu[1][0], a1); a1 = FDOT2(z0.y, Xu[1][1], a1);   \
            a1 = FDOT2(z0.z, Xu[1][2], a1); a1 = FDOT2(z0.w, Xu[1][3], a1);   \
            b1 = FDOT2(z1.x, Xu[1][4], b1); b1 = FDOT2(z1.y, Xu[1][5], b1);   \
            b1 = FDOT2(z1.z, Xu[1][6], b1); b1 = FDOT2(z1.w, Xu[1][7], b1);   \
            const float dd0 = fmaf(M2L, a0 + b0, xs2[0] + zz);                \
            const float dd1 = fmaf(M2L, a1 + b1, xs2[1] + zz);                \
            rg[wb_ + cc] = pk(dd0, dd1);                                      \
        }                                                                     \
    }

    // pre-loop: band 0's tiles 0,1 (consumed at s=0) behind one barrier
    if (wv >= 4 && bd == 0) { PRODUCE(0) PRODUCE(1) }
    __syncthreads();

    // ---- DP state (producers carry these dead) ----
    float RpK[2], RpS[2], poK, poS, bnK, bnS;
    unsigned rv[2];                  // ring prefetch slots (parity of tl)
    RpK[0] = RpK[1] = BIGS; RpS[0] = RpS[1] = 1.0f;
    poK = BIGS; poS = 1.0f; bnK = BIGS; bnS = 1.0f;
    rv[0] = rv[1] = 0u;

// q must equal (tl)&1 at each expansion (tb is even). ALLOK: compile-time
// "every lane valid" (interior supersteps) -> masks fold away.
#define TICK(q, tl, ALLOK)                                                    \
    {                                                                         \
        const float2 sprev = rKS[((tl) + 1) & 63];  /* seam, read@c-1 */      \
        const float unK = bnK, unS = bnS;                                     \
        const h2 dh = __builtin_bit_cast(h2, rv[q]);                          \
        rv[q] = rg[((unsigned)((tl) + 2 - t)) & 127];  /* for tick tl+2 */    \
        const float dd0 = (float)dh.x;                                        \
        const float dd1 = (float)dh.y;                                        \
        const float l0K = RpK[0], l0S = RpS[0];                               \
        const float m0 = fminf(fminf(unK, l0K), poK);                         \
        const float s0 = EXP2F(m0 - unK) * unS                                \
                       + EXP2F(m0 - l0K) * l0S                                \
                       + EXP2F(m0 - poK) * poS;                               \
        const float K0 = dd0 + m0;                                            \
        const float l1K = RpK[1], l1S = RpS[1];                               \
        const float m1 = fminf(fminf(K0, l1K), l0K);                          \
        const float s1 = EXP2F(m1 - K0) * s0                                  \
                       + EXP2F(m1 - l1K) * l1S                                \
                       + EXP2F(m1 - l0K) * l0S;                               \
        const float K1 = dd1 + m1;                                            \
        const int j = (tl) - t;                                               \
        const bool ok = (ALLOK) ? true : ((j >= 0) && (j < 512));             \
        RpK[0] = ok ? K0 : RpK[0];  RpS[0] = ok ? s0 : RpS[0];                \
        RpK[1] = ok ? K1 : RpK[1];  RpS[1] = ok ? s1 : RpS[1];                \
        if (ok && bd < 3 && t == 63) {                                        \
            seam[bd + 1][j & 63] = make_float2(RpK[1], RpS[1]);               \
        }                                                                     \
        poK = unK; poS = unS;                                                 \
        bnK = dppshr1(RpK[1], sprev.x);        /* boundary for tick tl+1 */   \
        bnS = dppshr1(RpS[1], sprev.y);                                       \
    }

#define RENORM                                                                \
    {                                                                         \
        _Pragma("unroll")                                                     \
        for (int q = 0; q < 2; ++q) {                                         \
            const int e = (int)(__float_as_uint(RpS[q]) >> 23) - 127;         \
            RpS[q] = __uint_as_float(__float_as_uint(RpS[q])                  \
                                     - ((unsigned)e << 23));                  \
            RpK[q] -= (float)e;                                               \
        }                                                                     \
    }

#define SS_BODY(A)                                                            \
    TICK(0, tb + 0, A)  TICK(1, tb + 1, A)  TICK(0, tb + 2, A)                \
    TICK(1, tb + 3, A)  TICK(0, tb + 4, A)  TICK(1, tb + 5, A)                \
    TICK(0, tb + 6, A)  TICK(1, tb + 7, A)                                    \
    RENORM                                                                    \
    TICK(0, tb + 8, A)  TICK(1, tb + 9, A)  TICK(0, tb + 10, A)               \
    TICK(1, tb + 11, A) TICK(0, tb + 12, A) TICK(1, tb + 13, A)               \
    TICK(0, tb + 14, A) TICK(1, tb + 15, A)                                   \
    RENORM

#pragma unroll 1
    for (int s = 0; s < N_SS; ++s) {
        if (wv >= 4) {
            // -------- producer wave: one 16-col tile, 2 supersteps ahead --
            const int T = s - 5 * bd + 2;
            if (T >= 0 && T <= 31) PRODUCE(T)
        } else {
            // -------- DP wave: 16 ticks of band bd --------
            const int tb = P_SS * s - G_LAG * bd;
            if (tb >= 64 && tb <= 496) {
                // interior: every lane/tick valid, masks folded away
                __builtin_amdgcn_s_setprio(1);
                SS_BODY(1)
                __builtin_amdgcn_s_setprio(0);
            } else if (tb >= 0 && tb <= 574) {
                if (tb == 0) {
                    // activation: DP state + boundary + ring prefetch
                    RpK[0] = RpK[1] = BIGS; RpS[0] = RpS[1] = 1.0f;
                    poK = (bd == 0 && t == 0) ? 0.0f : BIGS; poS = 1.0f;
                    const float2 r0 = rKS[0];
                    bnK = r0.x; bnS = r0.y;   // un(tick0): lane0 real
                    rv[0] = rg[((unsigned)(0 - t)) & 127];   // col 0-t (tick 0)
                    rv[1] = rg[((unsigned)(1 - t)) & 127];   // col 1-t (tick 1)
                }
                __builtin_amdgcn_s_setprio(1);
                SS_BODY(0)
                __builtin_amdgcn_s_setprio(0);
            }
        }
        __syncthreads();
    }
#undef TICK
#undef RENORM
#undef SS_BODY
#undef PRODUCE

    // band 3, lane 63, row 511 at tick 574 -> R(511,511) = K - log2(sm)
    if (wv == 3 && t == 63) {
        atomicAdd(out, wgt * (RpK[1] - log2f(RpS[1])) * LN2F);
    }
}

__global__ void k_zero(float* out) {
    if (threadIdx.x == 0) out[0] = 0.0f;
}

extern "C" void kernel_launch(void* const* d_in, const int* in_sizes, int n_in,
                              void* d_out, int out_size, void* d_ws, size_t ws_size,
                              hipStream_t stream) {
    const float* X = (const float*)d_in[0];   // (64, 512, 16) f32
    const float* w = (const float*)d_in[1];   // (64,) f32
    const float* Z = (const float*)d_in[2];   // (512, 16) f32
    float* out = (float*)d_out;               // scalar f32

    hipLaunchKernelGGL(k_zero, dim3(1), dim3(64), 0, stream, out);
    hipLaunchKernelGGL(k_fused, dim3(64), dim3(512), 0, stream, X, Z, w, out);
}

// Round 8
// 166.650 us; speedup vs baseline: 3.5464x; 1.0307x over previous
//
#include <hip/hip_runtime.h>

#define TT 512
#define BIGS 1.4426950408889634e10f   // BIG(1e10) * log2(e), scaled domain
#define LOG2E 1.4426950408889634f
#define M2L  (-2.0f * 1.4426950408889634f)
#define LN2F 0.69314718055994531f
#define P_SS 16                       // ticks per superstep (barrier period)
#define G_LAG 80                      // band lag (r17-verified margins)
#define N_SS 51                       // band3 last tick 574+240=814 -> s=50
#define RSTR 130                      // ring row stride (words); 128 slots + pad

typedef _Float16 h2 __attribute__((ext_vector_type(2)));

__device__ __forceinline__ unsigned pk(float a, float b) {
    h2 v; v.x = (_Float16)a; v.y = (_Float16)b;
    return __builtin_bit_cast(unsigned, v);
}

#if __has_builtin(__builtin_amdgcn_fdot2)
#define FDOT2(a, b, c) __builtin_amdgcn_fdot2(__builtin_bit_cast(h2, (a)), \
                                              __builtin_bit_cast(h2, (b)), (c), false)
#else
__device__ __forceinline__ float fdot2_sw(unsigned a, unsigned b, float c) {
    h2 ha = __builtin_bit_cast(h2, a), hb = __builtin_bit_cast(h2, b);
    return c + (float)ha.x * (float)hb.x + (float)ha.y * (float)hb.y;
}
#define FDOT2(a, b, c) fdot2_sw((a), (b), (c))
#endif

#if __has_builtin(__builtin_amdgcn_exp2f)
#define EXP2F(x) __builtin_amdgcn_exp2f(x)
#else
#define EXP2F(x) exp2f(x)
#endif

// permuted Z index, pure bitops (valid for any int j; wraps out-of-range j
// onto some valid row -- garbage rows only feed masked ticks)
#define ZROW(jv) (((((jv) & 1)) << 8) | ((((jv) >> 1)) & 255))

// lane-shift-up-by-1 via DPP wave_shr:1 (VALU) on the loop-carried path.
// Lane 0 takes `old` = seam value. Verified r13/r14/r16/r17.
__device__ __forceinline__ float dppshr1(float x, float old) {
#if __has_builtin(__builtin_amdgcn_update_dpp)
    return __builtin_bit_cast(float,
        __builtin_amdgcn_update_dpp(__builtin_bit_cast(int, old),
                                    __builtin_bit_cast(int, x),
                                    0x138 /*wave_shr:1*/, 0xF, 0xF, false));
#else
    const float v = __shfl_up(x, 1);
    return ((threadIdx.x & 63) == 0) ? old : v;
#endif
}

// ---------------------------------------------------------------------------
// Round 18 = r17 (117.6us kernel, verified) + 3rd independent wave per SIMD.
// Issue accounting: DP tick issue ~190cy (6x v_exp_f32 @ quarter-rate = 96cy
// + ~60 VALU + LDS + DPP); producer ~50cy; measured wall 346cy -> ~50%
// stall. Producers are split into per-half-tile waves:
//   waves 0..3  : DP bands 0..3            (unchanged)
//   waves 4..7  : producer half A, cols 0..7 of each 16-col tile
//   waves 8..11 : producer half B, cols 8..15
// bd = wv & 3 for all roles -> SIMD k hosts {DP k, prodA k, prodB k} = 3
// independent instruction streams to fill DP dependency stalls.
// Ring layout, pacing (T = s - 5*bd + 2), margins, DP tick math: byte-
// identical to r17 (the halves write disjoint slots on the same schedule;
// r16/r17 correctness proof carries over).
// ---------------------------------------------------------------------------
__global__ __launch_bounds__(768, 1) void k_fused(const float* __restrict__ X,
                                                  const float* __restrict__ Z,
                                                  const float* __restrict__ w,
                                                  float* __restrict__ out) {
    const int tt = threadIdx.x;
    const int t  = tt & 63;          // lane
    const int wv = tt >> 6;          // wave 0..11
    const int bd = wv & 3;           // band this wave serves
    const int hf = (wv >= 8) ? 1 : 0;// producer half (wv>=4 only)
    const int n  = blockIdx.x;       // sample

    __shared__ uint4    ZA[2][512];  // Z rows fp16-packed, permuted idx
    __shared__ float    Zs2p[512];   // LOG2E*|z|^2 at permuted idx
    __shared__ float2   seam[4][64]; // seam rings (K, sm); band0 = border
    __shared__ unsigned ring[4][64][RSTR];  // fp16x2 dd pairs, slot = col&127

    // ---- stage Z into LDS: threads 0..511 handle one row each ----
    if (tt < 512) {
        const int r = tt;
        const float4* zp = (const float4*)(Z + (size_t)r * 16);
        const float4 a0 = zp[0], a1 = zp[1], a2 = zp[2], a3 = zp[3];
        float sv = 0.0f;
        sv = fmaf(a0.x, a0.x, sv); sv = fmaf(a0.y, a0.y, sv);
        sv = fmaf(a0.z, a0.z, sv); sv = fmaf(a0.w, a0.w, sv);
        sv = fmaf(a1.x, a1.x, sv); sv = fmaf(a1.y, a1.y, sv);
        sv = fmaf(a1.z, a1.z, sv); sv = fmaf(a1.w, a1.w, sv);
        sv = fmaf(a2.x, a2.x, sv); sv = fmaf(a2.y, a2.y, sv);
        sv = fmaf(a2.z, a2.z, sv); sv = fmaf(a2.w, a2.w, sv);
        sv = fmaf(a3.x, a3.x, sv); sv = fmaf(a3.y, a3.y, sv);
        sv = fmaf(a3.z, a3.z, sv); sv = fmaf(a3.w, a3.w, sv);
        const int idx = ((r & 1) << 8) | (r >> 1);
        ZA[0][idx] = make_uint4(pk(a0.x, a0.y), pk(a0.z, a0.w),
                                pk(a1.x, a1.y), pk(a1.z, a1.w));
        ZA[1][idx] = make_uint4(pk(a2.x, a2.y), pk(a2.z, a2.w),
                                pk(a3.x, a3.y), pk(a3.z, a3.w));
        Zs2p[idx] = LOG2E * sv;
    }
    // seam rings -> (BIGS, 1): matrix border; band-0 ring never written.
    if (tt < 256) ((float2*)&seam[0][0])[tt] = make_float2(BIGS, 1.0f);

    // ---- X rows for band bd, lane t (rows i0, i0+1) -> registers ----
    const int i0 = 128 * bd + 2 * t;
    unsigned Xu[2][8];
    float    xs2[2];
    const float* xp = X + ((size_t)n * TT + i0) * 16;
#pragma unroll
    for (int q = 0; q < 2; ++q) {
        const float4* xr = (const float4*)(xp + q * 16);
        const float4 a0 = xr[0], a1 = xr[1], a2 = xr[2], a3 = xr[3];
        float sv = 0.0f;
        sv = fmaf(a0.x, a0.x, sv); sv = fmaf(a0.y, a0.y, sv);
        sv = fmaf(a0.z, a0.z, sv); sv = fmaf(a0.w, a0.w, sv);
        sv = fmaf(a1.x, a1.x, sv); sv = fmaf(a1.y, a1.y, sv);
        sv = fmaf(a1.z, a1.z, sv); sv = fmaf(a1.w, a1.w, sv);
        sv = fmaf(a2.x, a2.x, sv); sv = fmaf(a2.y, a2.y, sv);
        sv = fmaf(a2.z, a2.z, sv); sv = fmaf(a2.w, a2.w, sv);
        sv = fmaf(a3.x, a3.x, sv); sv = fmaf(a3.y, a3.y, sv);
        sv = fmaf(a3.z, a3.z, sv); sv = fmaf(a3.w, a3.w, sv);
        xs2[q] = LOG2E * sv;
        Xu[q][0] = pk(a0.x, a0.y); Xu[q][1] = pk(a0.z, a0.w);
        Xu[q][2] = pk(a1.x, a1.y); Xu[q][3] = pk(a1.z, a1.w);
        Xu[q][4] = pk(a2.x, a2.y); Xu[q][5] = pk(a2.z, a2.w);
        Xu[q][6] = pk(a3.x, a3.y); Xu[q][7] = pk(a3.z, a3.w);
    }
    const float wgt = w[n];
    const float2* rKS = &seam[bd][0];
    unsigned* const rg = &ring[bd][t][0];
    __syncthreads();

    // producer: fp16-packed dd pair for 8 cols of tile Tv (half hf)
#define PRODUCE(Tv)                                                           \
    {                                                                         \
        const int base_ = ((Tv) << 4) + (hf << 3);                            \
        const int wb_ = base_ & 127;                                          \
        _Pragma("unroll 4")                                                   \
        for (int cc = 0; cc < 8; ++cc) {                                      \
            const int zr = ZROW(base_ + cc);       /* wave-uniform */         \
            const uint4 z0 = ZA[0][zr], z1 = ZA[1][zr];                       \
            const float zz = Zs2p[zr];                                        \
            float a0 = 0.0f, b0 = 0.0f, a1 = 0.0f, b1 = 0.0f;                 \
            a0 = FDOT2(z0.x, Xu[0][0], a0); a0 = FDOT2(z0.y, Xu[0][1], a0);   \
            a0 = FDOT2(z0.z, Xu[0][2], a0); a0 = FDOT2(z0.w, Xu[0][3], a0);   \
            b0 = FDOT2(z1.x, Xu[0][4], b0); b0 = FDOT2(z1.y, Xu[0][5], b0);   \
            b0 = FDOT2(z1.z, Xu[0][6], b0); b0 = FDOT2(z1.w, Xu[0][7], b0);   \
            a1 = FDOT2(z0.x, Xu[1][0], a1); a1 = FDOT2(z0.y, Xu[1][1], a1);   \
            a1 = FDOT2(z0.z, Xu[1][2], a1); a1 = FDOT2(z0.w, Xu[1][3], a1);   \
            b1 = FDOT2(z1.x, Xu[1][4], b1); b1 = FDOT2(z1.y, Xu[1][5], b1);   \
            b1 = FDOT2(z1.z, Xu[1][6], b1); b1 = FDOT2(z1.w, Xu[1][7], b1);   \
            const float dd0 = fmaf(M2L, a0 + b0, xs2[0] + zz);                \
            const float dd1 = fmaf(M2L, a1 + b1, xs2[1] + zz);                \
            rg[wb_ + cc] = pk(dd0, dd1);                                      \
        }                                                                     \
    }

    // pre-loop: band 0's tiles 0,1 (consumed at s=0) behind one barrier
    if (wv >= 4 && bd == 0) { PRODUCE(0) PRODUCE(1) }
    __syncthreads();

    // ---- DP state (producers carry these dead) ----
    float RpK[2], RpS[2], poK, poS, bnK, bnS;
    unsigned rv[2];                  // ring prefetch slots (parity of tl)
    RpK[0] = RpK[1] = BIGS; RpS[0] = RpS[1] = 1.0f;
    poK = BIGS; poS = 1.0f; bnK = BIGS; bnS = 1.0f;
    rv[0] = rv[1] = 0u;

// q must equal (tl)&1 at each expansion (tb is even). ALLOK: compile-time
// "every lane valid" (interior supersteps) -> masks fold away.
#define TICK(q, tl, ALLOK)                                                    \
    {                                                                         \
        const float2 sprev = rKS[((tl) + 1) & 63];  /* seam, read@c-1 */      \
        const float unK = bnK, unS = bnS;                                     \
        const h2 dh = __builtin_bit_cast(h2, rv[q]);                          \
        rv[q] = rg[((unsigned)((tl) + 2 - t)) & 127];  /* for tick tl+2 */    \
        const float dd0 = (float)dh.x;                                        \
        const float dd1 = (float)dh.y;                                        \
        const float l0K = RpK[0], l0S = RpS[0];                               \
        const float m0 = fminf(fminf(unK, l0K), poK);                         \
        const float s0 = EXP2F(m0 - unK) * unS                                \
                       + EXP2F(m0 - l0K) * l0S                                \
                       + EXP2F(m0 - poK) * poS;                               \
        const float K0 = dd0 + m0;                                            \
        const float l1K = RpK[1], l1S = RpS[1];                               \
        const float m1 = fminf(fminf(K0, l1K), l0K);                          \
        const float s1 = EXP2F(m1 - K0) * s0                                  \
                       + EXP2F(m1 - l1K) * l1S                                \
                       + EXP2F(m1 - l0K) * l0S;                               \
        const float K1 = dd1 + m1;                                            \
        const int j = (tl) - t;                                               \
        const bool ok = (ALLOK) ? true : ((j >= 0) && (j < 512));             \
        RpK[0] = ok ? K0 : RpK[0];  RpS[0] = ok ? s0 : RpS[0];                \
        RpK[1] = ok ? K1 : RpK[1];  RpS[1] = ok ? s1 : RpS[1];                \
        if (ok && bd < 3 && t == 63) {                                        \
            seam[bd + 1][j & 63] = make_float2(RpK[1], RpS[1]);               \
        }                                                                     \
        poK = unK; poS = unS;                                                 \
        bnK = dppshr1(RpK[1], sprev.x);        /* boundary for tick tl+1 */   \
        bnS = dppshr1(RpS[1], sprev.y);                                       \
    }

#define RENORM                                                                \
    {                                                                         \
        _Pragma("unroll")                                                     \
        for (int q = 0; q < 2; ++q) {                                         \
            const int e = (int)(__float_as_uint(RpS[q]) >> 23) - 127;         \
            RpS[q] = __uint_as_float(__float_as_uint(RpS[q])                  \
                                     - ((unsigned)e << 23));                  \
            RpK[q] -= (float)e;                                               \
        }                                                                     \
    }

#define SS_BODY(A)                                                            \
    TICK(0, tb + 0, A)  TICK(1, tb + 1, A)  TICK(0, tb + 2, A)                \
    TICK(1, tb + 3, A)  TICK(0, tb + 4, A)  TICK(1, tb + 5, A)                \
    TICK(0, tb + 6, A)  TICK(1, tb + 7, A)                                    \
    RENORM                                                                    \
    TICK(0, tb + 8, A)  TICK(1, tb + 9, A)  TICK(0, tb + 10, A)               \
    TICK(1, tb + 11, A) TICK(0, tb + 12, A) TICK(1, tb + 13, A)               \
    TICK(0, tb + 14, A) TICK(1, tb + 15, A)                                   \
    RENORM

#pragma unroll 1
    for (int s = 0; s < N_SS; ++s) {
        if (wv >= 4) {
            // -------- producer wave: 8 cols of one tile, 2 ss ahead --------
            const int T = s - 5 * bd + 2;
            if (T >= 0 && T <= 31) PRODUCE(T)
        } else {
            // -------- DP wave: 16 ticks of band bd --------
            const int tb = P_SS * s - G_LAG * bd;
            if (tb >= 64 && tb <= 496) {
                // interior: every lane/tick valid, masks folded away
                __builtin_amdgcn_s_setprio(1);
                SS_BODY(1)
                __builtin_amdgcn_s_setprio(0);
            } else if (tb >= 0 && tb <= 574) {
                if (tb == 0) {
                    // activation: DP state + boundary + ring prefetch
                    RpK[0] = RpK[1] = BIGS; RpS[0] = RpS[1] = 1.0f;
                    poK = (bd == 0 && t == 0) ? 0.0f : BIGS; poS = 1.0f;
                    const float2 r0 = rKS[0];
                    bnK = r0.x; bnS = r0.y;   // un(tick0): lane0 real
                    rv[0] = rg[((unsigned)(0 - t)) & 127];   // col 0-t (tick 0)
                    rv[1] = rg[((unsigned)(1 - t)) & 127];   // col 1-t (tick 1)
                }
                __builtin_amdgcn_s_setprio(1);
                SS_BODY(0)
                __builtin_amdgcn_s_setprio(0);
            }
        }
        __syncthreads();
    }
#undef TICK
#undef RENORM
#undef SS_BODY
#undef PRODUCE

    // band 3, lane 63, row 511 at tick 574 -> R(511,511) = K - log2(sm)
    if (wv == 3 && t == 63) {
        atomicAdd(out, wgt * (RpK[1] - log2f(RpS[1])) * LN2F);
    }
}

__global__ void k_zero(float* out) {
    if (threadIdx.x == 0) out[0] = 0.0f;
}

extern "C" void kernel_launch(void* const* d_in, const int* in_sizes, int n_in,
                              void* d_out, int out_size, void* d_ws, size_t ws_size,
                              hipStream_t stream) {
    const float* X = (const float*)d_in[0];   // (64, 512, 16) f32
    const float* w = (const float*)d_in[1];   // (64,) f32
    const float* Z = (const float*)d_in[2];   // (512, 16) f32
    float* out = (float*)d_out;               // scalar f32

    hipLaunchKernelGGL(k_zero, dim3(1), dim3(64), 0, stream, out);
    hipLaunchKernelGGL(k_fused, dim3(64), dim3(768), 0, stream, X, Z, w, out);
}